// Round 12
// baseline (316.365 us; speedup 1.0000x reference)
//
#include <hip/hip_runtime.h>

constexpr int NN = 100000;
constexpr int NE = 800000;
constexpr int SCAN_CHUNK = 512;
constexpr int NBLK = (NN + SCAN_CHUNK - 1) / SCAN_CHUNK;   // 196
constexpr int KTOT = 288;          // 128 (x) + 128 (mean) + 32 (aggE)
constexpr int NOCT = KTOT / 8;     // 36 k-octets

constexpr int CASTX_BLOCKS = (NN * 128 / 8 + 255) / 256;   // 6250
constexpr int HIST_BLOCKS  = 2048;
constexpr int PREP_BLOCKS  = (KTOT * 128 + 128 + 255) / 256; // 145

typedef short bf16x8 __attribute__((ext_vector_type(8)));
typedef float f32x4  __attribute__((ext_vector_type(4)));

__device__ inline ushort f2b(float f) {
    uint u = __builtin_bit_cast(uint, f);
    u += 0x7FFF + ((u >> 16) & 1);
    return (ushort)(u >> 16);
}
__device__ inline float b2f(ushort h) {
    uint u = (uint)h << 16;
    return __builtin_bit_cast(float, u);
}

// ---------------------------------------------------------------------------
// prep body: Btp[NOCT][128][8] bf16 (pre-transposed B) + r vector
__device__ inline void prep_body(int i, const float* __restrict__ Wn,
                                 const float* __restrict__ bn,
                                 const float* __restrict__ We,
                                 const float* __restrict__ be,
                                 const float* __restrict__ Wu,
                                 ushort* __restrict__ Btp, float* __restrict__ r) {
    if (i < KTOT * 128) {
        int K = i >> 7, col = i & 127;
        float v;
        if (K < 128) {
            v = Wu[(size_t)K * 128 + col];
        } else if (K < 256) {
            const float* Wubot = Wu + 128 * 128;
            float s = 0.f;
            for (int m = 0; m < 128; m++)
                s = fmaf(Wn[(K - 128) * 128 + m], Wubot[m * 128 + col], s);
            v = s;
        } else {
            const float* Wubot = Wu + 128 * 128;
            float s = 0.f;
            for (int m = 0; m < 128; m++)
                s = fmaf(We[(K - 256) * 128 + m], Wubot[m * 128 + col], s);
            v = s;
        }
        Btp[(size_t)(K >> 3) * 1024 + col * 8 + (K & 7)] = f2b(v);
    } else if (i < KTOT * 128 + 128) {
        int col = i - KTOT * 128;
        const float* Wubot = Wu + 128 * 128;
        float s = 0.f;
        for (int m = 0; m < 128; m++)
            s = fmaf(bn[m] + be[m], Wubot[m * 128 + col], s);
        r[col] = s;
    }
}

// ---------------------------------------------------------------------------
// merged setup: prep1 | prep2 | castx | hist
__global__ __launch_bounds__(256)
void init_kernel(const float* __restrict__ x, ushort* __restrict__ Xb,
                 const int* __restrict__ dst, int* __restrict__ hist,
                 const float* __restrict__ Wn1, const float* __restrict__ bn1,
                 const float* __restrict__ We1, const float* __restrict__ be1,
                 const float* __restrict__ Wu1,
                 ushort* __restrict__ Btp1, float* __restrict__ r1,
                 const float* __restrict__ Wn2, const float* __restrict__ bn2,
                 const float* __restrict__ We2, const float* __restrict__ be2,
                 const float* __restrict__ Wu2,
                 ushort* __restrict__ Btp2, float* __restrict__ r2) {
    int b = blockIdx.x;
    if (b < PREP_BLOCKS) {
        int i = b * 256 + threadIdx.x;
        prep_body(i, Wn1, bn1, We1, be1, Wu1, Btp1, r1);
    } else if (b < 2 * PREP_BLOCKS) {
        int i = (b - PREP_BLOCKS) * 256 + threadIdx.x;
        prep_body(i, Wn2, bn2, We2, be2, Wu2, Btp2, r2);
    } else if (b < 2 * PREP_BLOCKS + CASTX_BLOCKS) {
        size_t i = ((size_t)(b - 2 * PREP_BLOCKS) * 256 + threadIdx.x) * 8;
        if (i >= (size_t)NN * 128) return;
        float4 v0 = *reinterpret_cast<const float4*>(&x[i]);
        float4 v1 = *reinterpret_cast<const float4*>(&x[i + 4]);
        ushort o[8] = {f2b(v0.x), f2b(v0.y), f2b(v0.z), f2b(v0.w),
                       f2b(v1.x), f2b(v1.y), f2b(v1.z), f2b(v1.w)};
        *reinterpret_cast<bf16x8*>(&Xb[i]) = *reinterpret_cast<bf16x8*>(o);
    } else {
        int bb = b - 2 * PREP_BLOCKS - CASTX_BLOCKS;
        for (int i = bb * 256 + threadIdx.x; i < NE; i += HIST_BLOCKS * 256)
            atomicAdd(&hist[dst[i]], 1);
    }
}

// ---------------------------------------------------------------------------
// scan1: per-chunk exclusive scan + chunk totals
__global__ __launch_bounds__(256)
void scan1_kernel(const int* __restrict__ hist, int* __restrict__ rp,
                  int* __restrict__ psum) {
    __shared__ int wsum[4];
    const int b = blockIdx.x, t = threadIdx.x;
    const int i0 = b * SCAN_CHUNK + 2 * t;
    int v0 = (i0     < NN) ? hist[i0]     : 0;
    int v1 = (i0 + 1 < NN) ? hist[i0 + 1] : 0;
    const int ts = v0 + v1;
    const int lane = t & 63, wid = t >> 6;
    int x = ts;
#pragma unroll
    for (int d = 1; d < 64; d <<= 1) {
        int n = __shfl_up(x, d, 64);
        if (lane >= d) x += n;
    }
    if (lane == 63) wsum[wid] = x;
    __syncthreads();
    int woff = (wid > 0 ? wsum[0] : 0) + (wid > 1 ? wsum[1] : 0) +
               (wid > 2 ? wsum[2] : 0);
    int incl = x + woff;
    int excl = incl - ts;
    if (i0     < NN) rp[i0]     = excl;
    if (i0 + 1 < NN) rp[i0 + 1] = excl + v0;
    if (t == 255) psum[b] = incl;
}

// scan2+3 merged
__global__ __launch_bounds__(256)
void scan23_kernel(int* __restrict__ rp, const int* __restrict__ psum) {
    __shared__ int wred[4];
    const int b = blockIdx.x, t = threadIdx.x;
    int val = (t < b) ? psum[t] : 0;    // b <= NBLK-1 < 256
    const int lane = t & 63, wid = t >> 6;
#pragma unroll
    for (int m = 1; m < 64; m <<= 1) val += __shfl_xor(val, m, 64);
    if (lane == 0) wred[wid] = val;
    __syncthreads();
    const int off = wred[0] + wred[1] + wred[2] + wred[3];
    const int i0 = b * SCAN_CHUNK + 2 * t;
    if (i0     < NN) rp[i0]     += off;
    if (i0 + 1 < NN) rp[i0 + 1] += off;
    if (b == 0 && t == 0) rp[NN] = NE;
}

// ---------------------------------------------------------------------------
// placement; hist counted DOWN to zero; ONE packed 8B write per edge
__global__ __launch_bounds__(256)
void place_kernel(const int* __restrict__ src, const int* __restrict__ dst,
                  const int* __restrict__ rp, int* __restrict__ hist,
                  int2* __restrict__ pairs, int E) {
    for (int e = blockIdx.x * blockDim.x + threadIdx.x; e < E;
         e += gridDim.x * blockDim.x) {
        int d = dst[e];
        int pos = rp[d] + atomicSub(&hist[d], 1) - 1;
        pairs[pos] = make_int2(src[e], e);
    }
}

// ---------------------------------------------------------------------------
// FUSED per-64-node-tile kernel:
//   phase 1: 4 waves x 16 nodes each — CSR gather (pair scheme) -> mean in LDS
//            (layer 1 also: aggE -> LDS + global, layer-invariant)
//   phase 2: 9-step MFMA GEMM (A = [Xsrc | meanLds | aggE]) + ReLU + LN
// Gather of block j overlaps MFMA of block i GPU-wide.
template<bool L1>   // L1: gather ea, write aggEb global, C -> bf16; else C -> f32
__global__ __launch_bounds__(256)
void fused_kernel(const ushort* __restrict__ Xsrc, const float* __restrict__ ea,
                  const int2* __restrict__ pairs, const int* __restrict__ rp,
                  ushort* __restrict__ aggEb_g,
                  const ushort* __restrict__ Btp, const float* __restrict__ r,
                  const float* __restrict__ bu, const float* __restrict__ g,
                  const float* __restrict__ beta,
                  float* __restrict__ Cf, ushort* __restrict__ Cb, int M) {
    __shared__ ushort meanLds[64][128];   // 16 KB
    __shared__ ushort aggELds[64][32];    // 4 KB (used only when L1)
    __shared__ float  invcLds[64];
    __shared__ ushort Als[4][64][8];      // 4 KB
    __shared__ ushort Bls[4][128][8];     // 8 KB
    __shared__ float ps[2][64], ps2[2][64];

    const int tid = threadIdx.x;
    const int w    = __builtin_amdgcn_readfirstlane(tid >> 6);
    const int lane = tid & 63;
    const int half = lane >> 5;
    const int l32  = lane & 31;
    const int brow = blockIdx.x * 64;

    // ================= phase 1: gather =================
    for (int t = 0; t < 16; t++) {
        const int row = w * 16 + t;
        const int v = brow + row;
        int beg = 0, end = 0;
        if (v < M) {
            beg = __builtin_amdgcn_readfirstlane(rp[v]);
            end = __builtin_amdgcn_readfirstlane(rp[v + 1]);
        }
        float a0 = 0.f, a1 = 0.f, a2 = 0.f, a3 = 0.f, aE = 0.f;
        int i = beg;
        for (; i + 7 < end; i += 8) {
            int2 p0 = pairs[i],     p1 = pairs[i + 1];
            int2 p2 = pairs[i + 2], p3 = pairs[i + 3];
            int2 p4 = pairs[i + 4], p5 = pairs[i + 5];
            int2 p6 = pairs[i + 6], p7 = pairs[i + 7];
            int s0 = __builtin_amdgcn_readfirstlane(p0.x);
            int s1 = __builtin_amdgcn_readfirstlane(p1.x);
            int s2 = __builtin_amdgcn_readfirstlane(p2.x);
            int s3 = __builtin_amdgcn_readfirstlane(p3.x);
            int s4 = __builtin_amdgcn_readfirstlane(p4.x);
            int s5 = __builtin_amdgcn_readfirstlane(p5.x);
            int s6 = __builtin_amdgcn_readfirstlane(p6.x);
            int s7 = __builtin_amdgcn_readfirstlane(p7.x);
            int sA = half ? s1 : s0, sB = half ? s3 : s2;
            int sC = half ? s5 : s4, sD = half ? s7 : s6;
            uint2 qA = *reinterpret_cast<const uint2*>(Xsrc + (size_t)sA * 128 + l32 * 4);
            uint2 qB = *reinterpret_cast<const uint2*>(Xsrc + (size_t)sB * 128 + l32 * 4);
            uint2 qC = *reinterpret_cast<const uint2*>(Xsrc + (size_t)sC * 128 + l32 * 4);
            uint2 qD = *reinterpret_cast<const uint2*>(Xsrc + (size_t)sD * 128 + l32 * 4);
            if (L1) {
                int e0 = __builtin_amdgcn_readfirstlane(p0.y);
                int e1 = __builtin_amdgcn_readfirstlane(p1.y);
                int e2 = __builtin_amdgcn_readfirstlane(p2.y);
                int e3 = __builtin_amdgcn_readfirstlane(p3.y);
                int e4 = __builtin_amdgcn_readfirstlane(p4.y);
                int e5 = __builtin_amdgcn_readfirstlane(p5.y);
                int e6 = __builtin_amdgcn_readfirstlane(p6.y);
                int e7 = __builtin_amdgcn_readfirstlane(p7.y);
                int eA = half ? e1 : e0, eB = half ? e3 : e2;
                int eC = half ? e5 : e4, eD = half ? e7 : e6;
                aE += (ea[(size_t)eA * 32 + l32] + ea[(size_t)eB * 32 + l32]) +
                      (ea[(size_t)eC * 32 + l32] + ea[(size_t)eD * 32 + l32]);
            }
            a0 += (b2f((ushort)qA.x) + b2f((ushort)qB.x)) +
                  (b2f((ushort)qC.x) + b2f((ushort)qD.x));
            a1 += (b2f((ushort)(qA.x >> 16)) + b2f((ushort)(qB.x >> 16))) +
                  (b2f((ushort)(qC.x >> 16)) + b2f((ushort)(qD.x >> 16)));
            a2 += (b2f((ushort)qA.y) + b2f((ushort)qB.y)) +
                  (b2f((ushort)qC.y) + b2f((ushort)qD.y));
            a3 += (b2f((ushort)(qA.y >> 16)) + b2f((ushort)(qB.y >> 16))) +
                  (b2f((ushort)(qC.y >> 16)) + b2f((ushort)(qD.y >> 16)));
        }
        if (i + 3 < end) {
            int2 p0 = pairs[i],     p1 = pairs[i + 1];
            int2 p2 = pairs[i + 2], p3 = pairs[i + 3];
            int s0 = __builtin_amdgcn_readfirstlane(p0.x);
            int s1 = __builtin_amdgcn_readfirstlane(p1.x);
            int s2 = __builtin_amdgcn_readfirstlane(p2.x);
            int s3 = __builtin_amdgcn_readfirstlane(p3.x);
            int sA = half ? s1 : s0, sB = half ? s3 : s2;
            uint2 qA = *reinterpret_cast<const uint2*>(Xsrc + (size_t)sA * 128 + l32 * 4);
            uint2 qB = *reinterpret_cast<const uint2*>(Xsrc + (size_t)sB * 128 + l32 * 4);
            if (L1) {
                int e0 = __builtin_amdgcn_readfirstlane(p0.y);
                int e1 = __builtin_amdgcn_readfirstlane(p1.y);
                int e2 = __builtin_amdgcn_readfirstlane(p2.y);
                int e3 = __builtin_amdgcn_readfirstlane(p3.y);
                int eA = half ? e1 : e0, eB = half ? e3 : e2;
                aE += ea[(size_t)eA * 32 + l32] + ea[(size_t)eB * 32 + l32];
            }
            a0 += b2f((ushort)qA.x) + b2f((ushort)qB.x);
            a1 += b2f((ushort)(qA.x >> 16)) + b2f((ushort)(qB.x >> 16));
            a2 += b2f((ushort)qA.y) + b2f((ushort)qB.y);
            a3 += b2f((ushort)(qA.y >> 16)) + b2f((ushort)(qB.y >> 16));
            i += 4;
        }
        if (i + 1 < end) {
            int2 p0 = pairs[i], p1 = pairs[i + 1];
            int s0 = __builtin_amdgcn_readfirstlane(p0.x);
            int s1 = __builtin_amdgcn_readfirstlane(p1.x);
            int sA = half ? s1 : s0;
            uint2 qA = *reinterpret_cast<const uint2*>(Xsrc + (size_t)sA * 128 + l32 * 4);
            if (L1) {
                int e0 = __builtin_amdgcn_readfirstlane(p0.y);
                int e1 = __builtin_amdgcn_readfirstlane(p1.y);
                int eA = half ? e1 : e0;
                aE += ea[(size_t)eA * 32 + l32];
            }
            a0 += b2f((ushort)qA.x);
            a1 += b2f((ushort)(qA.x >> 16));
            a2 += b2f((ushort)qA.y);
            a3 += b2f((ushort)(qA.y >> 16));
            i += 2;
        }
        if (i < end) {
            int2 p0 = pairs[i];
            int s0 = __builtin_amdgcn_readfirstlane(p0.x);
            if (half == 0) {
                uint2 qA = *reinterpret_cast<const uint2*>(Xsrc + (size_t)s0 * 128 + l32 * 4);
                a0 += b2f((ushort)qA.x);
                a1 += b2f((ushort)(qA.x >> 16));
                a2 += b2f((ushort)qA.y);
                a3 += b2f((ushort)(qA.y >> 16));
                if (L1) {
                    int e0 = __builtin_amdgcn_readfirstlane(p0.y);
                    aE += ea[(size_t)e0 * 32 + l32];
                }
            }
        }
        a0 += __shfl_xor(a0, 32, 64);
        a1 += __shfl_xor(a1, 32, 64);
        a2 += __shfl_xor(a2, 32, 64);
        a3 += __shfl_xor(a3, 32, 64);
        if (L1) aE += __shfl_xor(aE, 32, 64);

        float inv = (end > beg) ? 1.0f / (float)(end - beg) : 0.0f;
        if (half == 0) {
            uint lo = (uint)f2b(a0 * inv) | ((uint)f2b(a1 * inv) << 16);
            uint hi = (uint)f2b(a2 * inv) | ((uint)f2b(a3 * inv) << 16);
            *reinterpret_cast<uint2*>(&meanLds[row][l32 * 4]) = make_uint2(lo, hi);
            if (L1) {
                ushort q = f2b(aE * inv);
                aggELds[row][l32] = q;
                if (v < M) aggEb_g[(size_t)v * 32 + l32] = q;
            }
        }
        if (lane == 0) invcLds[row] = inv;
    }
    __syncthreads();

    // ================= phase 2: MFMA GEMM =================
    const int wr = (tid >> 6) >> 1, wc = (tid >> 6) & 1;
    const int lo4 = lane >> 4, li = lane & 15;

    f32x4 acc[2][4];
#pragma unroll
    for (int fr = 0; fr < 2; fr++)
#pragma unroll
        for (int fc = 0; fc < 4; fc++) acc[fr][fc] = (f32x4)0.f;

    const int arow = tid & 63;
    const int akc  = tid >> 6;
    const int grow = brow + arow;

    for (int step = 0; step < 9; step++) {
        {
            int kg = step * 4 + akc;
            bf16x8 vv = (bf16x8)0;
            if (kg < 16) {
                if (grow < M)
                    vv = *reinterpret_cast<const bf16x8*>(Xsrc + (size_t)grow * 128 + kg * 8);
            } else if (kg < 32) {
                vv = *reinterpret_cast<const bf16x8*>(&meanLds[arow][(kg - 16) * 8]);
            } else {
                if (L1) vv = *reinterpret_cast<const bf16x8*>(&aggELds[arow][(kg - 32) * 8]);
                else if (grow < M)
                    vv = *reinterpret_cast<const bf16x8*>(aggEb_g + (size_t)grow * 32 + (kg - 32) * 8);
            }
            *reinterpret_cast<bf16x8*>(&Als[akc][arow][0]) = vv;
        }
#pragma unroll
        for (int h = 0; h < 2; h++) {
            int u = tid + h * 256;
            int kcl = u >> 7, col = u & 127;
            *reinterpret_cast<bf16x8*>(&Bls[kcl][col][0]) =
                *reinterpret_cast<const bf16x8*>(
                    Btp + ((size_t)(step * 4 + kcl) * 128 + col) * 8);
        }
        __syncthreads();

        bf16x8 a0f = *reinterpret_cast<const bf16x8*>(&Als[lo4][wr * 32 + li][0]);
        bf16x8 a1f = *reinterpret_cast<const bf16x8*>(&Als[lo4][wr * 32 + 16 + li][0]);
#pragma unroll
        for (int fc = 0; fc < 4; fc++) {
            bf16x8 b = *reinterpret_cast<const bf16x8*>(&Bls[lo4][wc * 64 + fc * 16 + li][0]);
            acc[0][fc] = __builtin_amdgcn_mfma_f32_16x16x32_bf16(a0f, b, acc[0][fc], 0, 0, 0);
            acc[1][fc] = __builtin_amdgcn_mfma_f32_16x16x32_bf16(a1f, b, acc[1][fc], 0, 0, 0);
        }
        __syncthreads();
    }

    // ---- epilogue: bias + has*r, relu, cross-wave layernorm, store
    float bu8[4], r8[4], g8[4], be8[4];
#pragma unroll
    for (int fc = 0; fc < 4; fc++) {
        int col = wc * 64 + fc * 16 + li;
        bu8[fc] = bu[col]; r8[fc] = r[col]; g8[fc] = g[col]; be8[fc] = beta[col];
    }

    float sv[2][4], s2v[2][4];
#pragma unroll
    for (int fr = 0; fr < 2; fr++)
#pragma unroll
        for (int j = 0; j < 4; j++) {
            int row64 = wr * 32 + fr * 16 + lo4 * 4 + j;
            float hv = (invcLds[row64] > 0.f) ? 1.f : 0.f;
            float s = 0.f, s2 = 0.f;
#pragma unroll
            for (int fc = 0; fc < 4; fc++) {
                float val = acc[fr][fc][j] + bu8[fc] + hv * r8[fc];
                val = fmaxf(val, 0.f);
                acc[fr][fc][j] = val;
                s += val; s2 += val * val;
            }
#pragma unroll
            for (int m = 1; m < 16; m <<= 1) {
                s  += __shfl_xor(s, m, 64);
                s2 += __shfl_xor(s2, m, 64);
            }
            sv[fr][j] = s; s2v[fr][j] = s2;
        }

    if (li == 0) {
#pragma unroll
        for (int fr = 0; fr < 2; fr++)
#pragma unroll
            for (int j = 0; j < 4; j++) {
                int row64 = wr * 32 + fr * 16 + lo4 * 4 + j;
                ps[wc][row64]  = sv[fr][j];
                ps2[wc][row64] = s2v[fr][j];
            }
    }
    __syncthreads();

#pragma unroll
    for (int fr = 0; fr < 2; fr++)
#pragma unroll
        for (int j = 0; j < 4; j++) {
            int row64 = wr * 32 + fr * 16 + lo4 * 4 + j;
            int gr = brow + row64;
            float s  = sv[fr][j]  + ps[1 - wc][row64];
            float s2 = s2v[fr][j] + ps2[1 - wc][row64];
            float mean = s * (1.0f / 128.0f);
            float var  = s2 * (1.0f / 128.0f) - mean * mean;
            float rstd = rsqrtf(var + 1e-5f);
            if (gr < M) {
#pragma unroll
                for (int fc = 0; fc < 4; fc++) {
                    int col = wc * 64 + fc * 16 + li;
                    float o = (acc[fr][fc][j] - mean) * rstd * g8[fc] + be8[fc];
                    if (L1) Cb[(size_t)gr * 128 + col] = f2b(o);
                    else    Cf[(size_t)gr * 128 + col] = o;
                }
            }
        }
}

// ---------------------------------------------------------------------------
extern "C" void kernel_launch(void* const* d_in, const int* in_sizes, int n_in,
                              void* d_out, int out_size, void* d_ws, size_t ws_size,
                              hipStream_t stream)
{
    const float* x    = (const float*)d_in[0];
    const int*   ei   = (const int*)d_in[1];
    const float* ea   = (const float*)d_in[2];
    const float* Wn1  = (const float*)d_in[3];
    const float* bn1  = (const float*)d_in[4];
    const float* We1  = (const float*)d_in[5];
    const float* be1  = (const float*)d_in[6];
    const float* Wu1  = (const float*)d_in[7];
    const float* bu1  = (const float*)d_in[8];
    const float* g1   = (const float*)d_in[9];
    const float* beta1= (const float*)d_in[10];
    const float* Wn2  = (const float*)d_in[11];
    const float* bn2  = (const float*)d_in[12];
    const float* We2  = (const float*)d_in[13];
    const float* be2  = (const float*)d_in[14];
    const float* Wu2  = (const float*)d_in[15];
    const float* bu2  = (const float*)d_in[16];
    const float* g2   = (const float*)d_in[17];
    const float* beta2= (const float*)d_in[18];

    const int* srcI = ei;
    const int* dstI = ei + NE;
    float* out = (float*)d_out;

    // ---- workspace layout
    int*   rp   = (int*)d_ws;                          // N+1
    int*   hist = rp + NN + 1;                         // N
    int*   psum = hist + NN;                           // 256
    uintptr_t pbase = ((uintptr_t)(psum + 256) + 7) & ~(uintptr_t)7;
    int2*  pairs = (int2*)pbase;                       // E (8B each)
    uintptr_t base = ((uintptr_t)(pairs + NE) + 15) & ~(uintptr_t)15;
    ushort* Xb    = (ushort*)base;                     // N*128 bf16 (x table)
    ushort* h1b   = Xb + (size_t)NN * 128;             // N*128 bf16 (h1 table)
    ushort* aggEb = h1b + (size_t)NN * 128;            // N*32
    ushort* Btp1  = aggEb + (size_t)NN * 32;           // 36*128*8
    ushort* Btp2  = Btp1 + NOCT * 1024;
    float*  r1    = (float*)(Btp2 + NOCT * 1024);      // 128
    float*  r2    = r1 + 128;

    const int gemm_grid = (NN + 63) / 64;

    // ---- setup: zero hist, then merged prep1|prep2|castx|hist
    hipMemsetAsync(hist, 0, NN * sizeof(int), stream);
    init_kernel<<<CASTX_BLOCKS + HIST_BLOCKS + 2 * PREP_BLOCKS, 256, 0, stream>>>(
        x, Xb, dstI, hist,
        Wn1, bn1, We1, be1, Wu1, Btp1, r1,
        Wn2, bn2, We2, be2, Wu2, Btp2, r2);

    // ---- CSR build
    scan1_kernel<<<NBLK, 256, 0, stream>>>(hist, rp, psum);
    scan23_kernel<<<NBLK, 256, 0, stream>>>(rp, psum);
    place_kernel<<<2048, 256, 0, stream>>>(srcI, dstI, rp, hist, pairs, NE);

    // ---- layer 1 fused (gather+GEMM); writes h1b + layer-invariant aggEb
    fused_kernel<true><<<gemm_grid, 256, 0, stream>>>(
        Xb, ea, pairs, rp, aggEb, Btp1, r1, bu1, g1, beta1, nullptr, h1b, NN);

    // ---- layer 2 fused; gathers h1b, writes f32 out
    fused_kernel<false><<<gemm_grid, 256, 0, stream>>>(
        h1b, ea, pairs, rp, aggEb, Btp2, r2, bu2, g2, beta2, out, nullptr, NN);
}

// Round 13
// 278.989 us; speedup vs baseline: 1.1340x; 1.1340x over previous
//
#include <hip/hip_runtime.h>

constexpr int NN = 100000;
constexpr int NE = 800000;
constexpr int SCAN_CHUNK = 512;
constexpr int NBLK = (NN + SCAN_CHUNK - 1) / SCAN_CHUNK;   // 196
constexpr int KTOT = 288;          // 128 (x) + 128 (mean) + 32 (aggE)
constexpr int NOCT = KTOT / 8;     // 36 k-octets

constexpr int CASTX_BLOCKS = (NN * 128 / 8 + 255) / 256;   // 6250
constexpr int HIST_BLOCKS  = 2048;
constexpr int PREP_BLOCKS  = (KTOT * 128 + 128 + 255) / 256; // 145

typedef short bf16x8 __attribute__((ext_vector_type(8)));
typedef float f32x4  __attribute__((ext_vector_type(4)));

__device__ inline ushort f2b(float f) {
    uint u = __builtin_bit_cast(uint, f);
    u += 0x7FFF + ((u >> 16) & 1);
    return (ushort)(u >> 16);
}
__device__ inline float b2f(ushort h) {
    uint u = (uint)h << 16;
    return __builtin_bit_cast(float, u);
}

// async global->LDS DMA, 16B per lane; lds dest = wave-uniform base + lane*16
__device__ inline void gload16(const void* g, void* l) {
    __builtin_amdgcn_global_load_lds(
        (const __attribute__((address_space(1))) void*)g,
        (__attribute__((address_space(3))) void*)l, 16, 0, 0);
}

// ---------------------------------------------------------------------------
// prep body: Btp[NOCT][128][8] bf16 (pre-transposed B) + r vector
__device__ inline void prep_body(int i, const float* __restrict__ Wn,
                                 const float* __restrict__ bn,
                                 const float* __restrict__ We,
                                 const float* __restrict__ be,
                                 const float* __restrict__ Wu,
                                 ushort* __restrict__ Btp, float* __restrict__ r) {
    if (i < KTOT * 128) {
        int K = i >> 7, col = i & 127;
        float v;
        if (K < 128) {
            v = Wu[(size_t)K * 128 + col];
        } else if (K < 256) {
            const float* Wubot = Wu + 128 * 128;
            float s = 0.f;
            for (int m = 0; m < 128; m++)
                s = fmaf(Wn[(K - 128) * 128 + m], Wubot[m * 128 + col], s);
            v = s;
        } else {
            const float* Wubot = Wu + 128 * 128;
            float s = 0.f;
            for (int m = 0; m < 128; m++)
                s = fmaf(We[(K - 256) * 128 + m], Wubot[m * 128 + col], s);
            v = s;
        }
        Btp[(size_t)(K >> 3) * 1024 + col * 8 + (K & 7)] = f2b(v);
    } else if (i < KTOT * 128 + 128) {
        int col = i - KTOT * 128;
        const float* Wubot = Wu + 128 * 128;
        float s = 0.f;
        for (int m = 0; m < 128; m++)
            s = fmaf(bn[m] + be[m], Wubot[m * 128 + col], s);
        r[col] = s;
    }
}

// ---------------------------------------------------------------------------
// merged setup: prep1 | prep2 | castx | hist
__global__ __launch_bounds__(256)
void init_kernel(const float* __restrict__ x, ushort* __restrict__ Xb,
                 const int* __restrict__ dst, int* __restrict__ hist,
                 const float* __restrict__ Wn1, const float* __restrict__ bn1,
                 const float* __restrict__ We1, const float* __restrict__ be1,
                 const float* __restrict__ Wu1,
                 ushort* __restrict__ Btp1, float* __restrict__ r1,
                 const float* __restrict__ Wn2, const float* __restrict__ bn2,
                 const float* __restrict__ We2, const float* __restrict__ be2,
                 const float* __restrict__ Wu2,
                 ushort* __restrict__ Btp2, float* __restrict__ r2) {
    int b = blockIdx.x;
    if (b < PREP_BLOCKS) {
        int i = b * 256 + threadIdx.x;
        prep_body(i, Wn1, bn1, We1, be1, Wu1, Btp1, r1);
    } else if (b < 2 * PREP_BLOCKS) {
        int i = (b - PREP_BLOCKS) * 256 + threadIdx.x;
        prep_body(i, Wn2, bn2, We2, be2, Wu2, Btp2, r2);
    } else if (b < 2 * PREP_BLOCKS + CASTX_BLOCKS) {
        size_t i = ((size_t)(b - 2 * PREP_BLOCKS) * 256 + threadIdx.x) * 8;
        if (i >= (size_t)NN * 128) return;
        float4 v0 = *reinterpret_cast<const float4*>(&x[i]);
        float4 v1 = *reinterpret_cast<const float4*>(&x[i + 4]);
        ushort o[8] = {f2b(v0.x), f2b(v0.y), f2b(v0.z), f2b(v0.w),
                       f2b(v1.x), f2b(v1.y), f2b(v1.z), f2b(v1.w)};
        *reinterpret_cast<bf16x8*>(&Xb[i]) = *reinterpret_cast<bf16x8*>(o);
    } else {
        int bb = b - 2 * PREP_BLOCKS - CASTX_BLOCKS;
        for (int i = bb * 256 + threadIdx.x; i < NE; i += HIST_BLOCKS * 256)
            atomicAdd(&hist[dst[i]], 1);
    }
}

// ---------------------------------------------------------------------------
// scan1: per-chunk exclusive scan + chunk totals
__global__ __launch_bounds__(256)
void scan1_kernel(const int* __restrict__ hist, int* __restrict__ rp,
                  int* __restrict__ psum) {
    __shared__ int wsum[4];
    const int b = blockIdx.x, t = threadIdx.x;
    const int i0 = b * SCAN_CHUNK + 2 * t;
    int v0 = (i0     < NN) ? hist[i0]     : 0;
    int v1 = (i0 + 1 < NN) ? hist[i0 + 1] : 0;
    const int ts = v0 + v1;
    const int lane = t & 63, wid = t >> 6;
    int x = ts;
#pragma unroll
    for (int d = 1; d < 64; d <<= 1) {
        int n = __shfl_up(x, d, 64);
        if (lane >= d) x += n;
    }
    if (lane == 63) wsum[wid] = x;
    __syncthreads();
    int woff = (wid > 0 ? wsum[0] : 0) + (wid > 1 ? wsum[1] : 0) +
               (wid > 2 ? wsum[2] : 0);
    int incl = x + woff;
    int excl = incl - ts;
    if (i0     < NN) rp[i0]     = excl;
    if (i0 + 1 < NN) rp[i0 + 1] = excl + v0;
    if (t == 255) psum[b] = incl;
}

// scan2+3 merged
__global__ __launch_bounds__(256)
void scan23_kernel(int* __restrict__ rp, const int* __restrict__ psum) {
    __shared__ int wred[4];
    const int b = blockIdx.x, t = threadIdx.x;
    int val = (t < b) ? psum[t] : 0;    // b <= NBLK-1 < 256
    const int lane = t & 63, wid = t >> 6;
#pragma unroll
    for (int m = 1; m < 64; m <<= 1) val += __shfl_xor(val, m, 64);
    if (lane == 0) wred[wid] = val;
    __syncthreads();
    const int off = wred[0] + wred[1] + wred[2] + wred[3];
    const int i0 = b * SCAN_CHUNK + 2 * t;
    if (i0     < NN) rp[i0]     += off;
    if (i0 + 1 < NN) rp[i0 + 1] += off;
    if (b == 0 && t == 0) rp[NN] = NE;
}

// ---------------------------------------------------------------------------
// placement; hist counted DOWN to zero; ONE packed 8B write per edge
__global__ __launch_bounds__(256)
void place_kernel(const int* __restrict__ src, const int* __restrict__ dst,
                  const int* __restrict__ rp, int* __restrict__ hist,
                  int2* __restrict__ pairs, int E) {
    for (int e = blockIdx.x * blockDim.x + threadIdx.x; e < E;
         e += gridDim.x * blockDim.x) {
        int d = dst[e];
        int pos = rp[d] + atomicSub(&hist[d], 1) - 1;
        pairs[pos] = make_int2(src[e], e);
    }
}

// ---------------------------------------------------------------------------
// CSR aggregation, edge-pair scheme (round-10 measured-best, unchanged)
template<bool DO_EA>
__global__ __launch_bounds__(256)
void agg_kernel(const ushort* __restrict__ Xb, const float* __restrict__ ea,
                const int2* __restrict__ pairs, const int* __restrict__ rp,
                ushort* __restrict__ meanb, ushort* __restrict__ aggEb,
                float* __restrict__ invc) {
    const int wid  = __builtin_amdgcn_readfirstlane(threadIdx.x >> 6);
    const int lane = threadIdx.x & 63;
    const int v = blockIdx.x * 4 + wid;
    if (v >= NN) return;
    const int beg = __builtin_amdgcn_readfirstlane(rp[v]);
    const int end = __builtin_amdgcn_readfirstlane(rp[v + 1]);
    const int half = lane >> 5;
    const int l32  = lane & 31;

    float a0 = 0.f, a1 = 0.f, a2 = 0.f, a3 = 0.f;
    float aE = 0.f;
    int i = beg;
    for (; i + 7 < end; i += 8) {
        int2 p0 = pairs[i],     p1 = pairs[i + 1];
        int2 p2 = pairs[i + 2], p3 = pairs[i + 3];
        int2 p4 = pairs[i + 4], p5 = pairs[i + 5];
        int2 p6 = pairs[i + 6], p7 = pairs[i + 7];
        int s0 = __builtin_amdgcn_readfirstlane(p0.x);
        int s1 = __builtin_amdgcn_readfirstlane(p1.x);
        int s2 = __builtin_amdgcn_readfirstlane(p2.x);
        int s3 = __builtin_amdgcn_readfirstlane(p3.x);
        int s4 = __builtin_amdgcn_readfirstlane(p4.x);
        int s5 = __builtin_amdgcn_readfirstlane(p5.x);
        int s6 = __builtin_amdgcn_readfirstlane(p6.x);
        int s7 = __builtin_amdgcn_readfirstlane(p7.x);
        int sA = half ? s1 : s0, sB = half ? s3 : s2;
        int sC = half ? s5 : s4, sD = half ? s7 : s6;
        uint2 qA = *reinterpret_cast<const uint2*>(Xb + (size_t)sA * 128 + l32 * 4);
        uint2 qB = *reinterpret_cast<const uint2*>(Xb + (size_t)sB * 128 + l32 * 4);
        uint2 qC = *reinterpret_cast<const uint2*>(Xb + (size_t)sC * 128 + l32 * 4);
        uint2 qD = *reinterpret_cast<const uint2*>(Xb + (size_t)sD * 128 + l32 * 4);
        if (DO_EA) {
            int e0 = __builtin_amdgcn_readfirstlane(p0.y);
            int e1 = __builtin_amdgcn_readfirstlane(p1.y);
            int e2 = __builtin_amdgcn_readfirstlane(p2.y);
            int e3 = __builtin_amdgcn_readfirstlane(p3.y);
            int e4 = __builtin_amdgcn_readfirstlane(p4.y);
            int e5 = __builtin_amdgcn_readfirstlane(p5.y);
            int e6 = __builtin_amdgcn_readfirstlane(p6.y);
            int e7 = __builtin_amdgcn_readfirstlane(p7.y);
            int eA = half ? e1 : e0, eB = half ? e3 : e2;
            int eC = half ? e5 : e4, eD = half ? e7 : e6;
            float fA = ea[(size_t)eA * 32 + l32];
            float fB = ea[(size_t)eB * 32 + l32];
            float fC = ea[(size_t)eC * 32 + l32];
            float fD = ea[(size_t)eD * 32 + l32];
            aE += (fA + fB) + (fC + fD);
        }
        a0 += (b2f((ushort)qA.x) + b2f((ushort)qB.x)) +
              (b2f((ushort)qC.x) + b2f((ushort)qD.x));
        a1 += (b2f((ushort)(qA.x >> 16)) + b2f((ushort)(qB.x >> 16))) +
              (b2f((ushort)(qC.x >> 16)) + b2f((ushort)(qD.x >> 16)));
        a2 += (b2f((ushort)qA.y) + b2f((ushort)qB.y)) +
              (b2f((ushort)qC.y) + b2f((ushort)qD.y));
        a3 += (b2f((ushort)(qA.y >> 16)) + b2f((ushort)(qB.y >> 16))) +
              (b2f((ushort)(qC.y >> 16)) + b2f((ushort)(qD.y >> 16)));
    }
    if (i + 3 < end) {
        int2 p0 = pairs[i],     p1 = pairs[i + 1];
        int2 p2 = pairs[i + 2], p3 = pairs[i + 3];
        int s0 = __builtin_amdgcn_readfirstlane(p0.x);
        int s1 = __builtin_amdgcn_readfirstlane(p1.x);
        int s2 = __builtin_amdgcn_readfirstlane(p2.x);
        int s3 = __builtin_amdgcn_readfirstlane(p3.x);
        int sA = half ? s1 : s0, sB = half ? s3 : s2;
        uint2 qA = *reinterpret_cast<const uint2*>(Xb + (size_t)sA * 128 + l32 * 4);
        uint2 qB = *reinterpret_cast<const uint2*>(Xb + (size_t)sB * 128 + l32 * 4);
        if (DO_EA) {
            int e0 = __builtin_amdgcn_readfirstlane(p0.y);
            int e1 = __builtin_amdgcn_readfirstlane(p1.y);
            int e2 = __builtin_amdgcn_readfirstlane(p2.y);
            int e3 = __builtin_amdgcn_readfirstlane(p3.y);
            int eA = half ? e1 : e0, eB = half ? e3 : e2;
            aE += ea[(size_t)eA * 32 + l32] + ea[(size_t)eB * 32 + l32];
        }
        a0 += b2f((ushort)qA.x) + b2f((ushort)qB.x);
        a1 += b2f((ushort)(qA.x >> 16)) + b2f((ushort)(qB.x >> 16));
        a2 += b2f((ushort)qA.y) + b2f((ushort)qB.y);
        a3 += b2f((ushort)(qA.y >> 16)) + b2f((ushort)(qB.y >> 16));
        i += 4;
    }
    if (i + 1 < end) {
        int2 p0 = pairs[i], p1 = pairs[i + 1];
        int s0 = __builtin_amdgcn_readfirstlane(p0.x);
        int s1 = __builtin_amdgcn_readfirstlane(p1.x);
        int sA = half ? s1 : s0;
        uint2 qA = *reinterpret_cast<const uint2*>(Xb + (size_t)sA * 128 + l32 * 4);
        if (DO_EA) {
            int e0 = __builtin_amdgcn_readfirstlane(p0.y);
            int e1 = __builtin_amdgcn_readfirstlane(p1.y);
            int eA = half ? e1 : e0;
            aE += ea[(size_t)eA * 32 + l32];
        }
        a0 += b2f((ushort)qA.x);
        a1 += b2f((ushort)(qA.x >> 16));
        a2 += b2f((ushort)qA.y);
        a3 += b2f((ushort)(qA.y >> 16));
        i += 2;
    }
    if (i < end) {
        int2 p0 = pairs[i];
        int s0 = __builtin_amdgcn_readfirstlane(p0.x);
        if (half == 0) {
            uint2 qA = *reinterpret_cast<const uint2*>(Xb + (size_t)s0 * 128 + l32 * 4);
            a0 += b2f((ushort)qA.x);
            a1 += b2f((ushort)(qA.x >> 16));
            a2 += b2f((ushort)qA.y);
            a3 += b2f((ushort)(qA.y >> 16));
            if (DO_EA) {
                int e0 = __builtin_amdgcn_readfirstlane(p0.y);
                aE += ea[(size_t)e0 * 32 + l32];
            }
        }
    }
    a0 += __shfl_xor(a0, 32, 64);
    a1 += __shfl_xor(a1, 32, 64);
    a2 += __shfl_xor(a2, 32, 64);
    a3 += __shfl_xor(a3, 32, 64);
    if (DO_EA) aE += __shfl_xor(aE, 32, 64);

    float inv = (end > beg) ? 1.0f / (float)(end - beg) : 0.0f;
    if (half == 0) {
        uint lo = (uint)f2b(a0 * inv) | ((uint)f2b(a1 * inv) << 16);
        uint hi = (uint)f2b(a2 * inv) | ((uint)f2b(a3 * inv) << 16);
        *reinterpret_cast<uint2*>(meanb + (size_t)v * 128 + l32 * 4) =
            make_uint2(lo, hi);
        if (DO_EA) aggEb[(size_t)v * 32 + l32] = f2b(aE * inv);
    }
    if (DO_EA && lane == 0) invc[v] = inv;
}

// ---------------------------------------------------------------------------
// fused MFMA GEMM, 64-row tile; staging via global_load_lds (16B DMA/lane).
// OOB rows (grow >= M) read adjacent ws arrays -> garbage, stores masked.
template<bool OUT_BF16>
__global__ __launch_bounds__(256)
void gemmF_kernel(const ushort* __restrict__ Xb, const ushort* __restrict__ meanb,
                  const ushort* __restrict__ aggEb, const float* __restrict__ invc,
                  const ushort* __restrict__ Btp, const float* __restrict__ r,
                  const float* __restrict__ bu, const float* __restrict__ g,
                  const float* __restrict__ beta,
                  float* __restrict__ Cf, ushort* __restrict__ Cb, int M) {
    __shared__ __align__(16) ushort Als[4][64][8];
    __shared__ __align__(16) ushort Bls[4][128][8];
    __shared__ float ps[2][64], ps2[2][64];

    const int tid = threadIdx.x;
    const int wid = tid >> 6, lane = tid & 63;
    const int wr = wid >> 1, wc = wid & 1;
    const int lo4 = lane >> 4, li = lane & 15;
    const int brow = blockIdx.x * 64;

    f32x4 acc[2][4];
#pragma unroll
    for (int fr = 0; fr < 2; fr++)
#pragma unroll
        for (int fc = 0; fc < 4; fc++) acc[fr][fc] = (f32x4)0.f;

    const int akc  = wid;               // wave id = staged k-octet
    const int grow = brow + lane;       // per-lane A row

    for (int step = 0; step < 9; step++) {
        // ---- stage A: one 16B DMA per lane into Als[akc][lane]
        {
            int kg = step * 4 + akc;    // wave-uniform
            const ushort* gA;
            if (kg < 16)      gA = Xb    + (size_t)grow * 128 + kg * 8;
            else if (kg < 32) gA = meanb + (size_t)grow * 128 + (kg - 16) * 8;
            else              gA = aggEb + (size_t)grow * 32  + (kg - 32) * 8;
            gload16(gA, &Als[akc][0][0]);
        }
        // ---- stage B: two 16B DMAs per lane, linear
#pragma unroll
        for (int h = 0; h < 2; h++) {
            int ub = h * 256 + akc * 64;            // wave-uniform chunk base
            gload16(Btp + ((size_t)step * 512 + ub + lane) * 8,
                    &Bls[0][0][0] + (size_t)ub * 8);
        }
        __syncthreads();

        bf16x8 a0 = *reinterpret_cast<const bf16x8*>(&Als[lo4][wr * 32 + li][0]);
        bf16x8 a1 = *reinterpret_cast<const bf16x8*>(&Als[lo4][wr * 32 + 16 + li][0]);
#pragma unroll
        for (int fc = 0; fc < 4; fc++) {
            bf16x8 b = *reinterpret_cast<const bf16x8*>(&Bls[lo4][wc * 64 + fc * 16 + li][0]);
            acc[0][fc] = __builtin_amdgcn_mfma_f32_16x16x32_bf16(a0, b, acc[0][fc], 0, 0, 0);
            acc[1][fc] = __builtin_amdgcn_mfma_f32_16x16x32_bf16(a1, b, acc[1][fc], 0, 0, 0);
        }
        __syncthreads();
    }

    float bu8[4], r8[4], g8[4], be8[4];
#pragma unroll
    for (int fc = 0; fc < 4; fc++) {
        int col = wc * 64 + fc * 16 + li;
        bu8[fc] = bu[col]; r8[fc] = r[col]; g8[fc] = g[col]; be8[fc] = beta[col];
    }

    float sv[2][4], s2v[2][4];
#pragma unroll
    for (int fr = 0; fr < 2; fr++)
#pragma unroll
        for (int j = 0; j < 4; j++) {
            int gr = brow + wr * 32 + fr * 16 + lo4 * 4 + j;
            float hv = 0.f;
            if (gr < M) hv = (invc[gr] > 0.f) ? 1.f : 0.f;
            float s = 0.f, s2 = 0.f;
#pragma unroll
            for (int fc = 0; fc < 4; fc++) {
                float val = acc[fr][fc][j] + bu8[fc] + hv * r8[fc];
                val = fmaxf(val, 0.f);
                acc[fr][fc][j] = val;
                s += val; s2 += val * val;
            }
#pragma unroll
            for (int m = 1; m < 16; m <<= 1) {
                s  += __shfl_xor(s, m, 64);
                s2 += __shfl_xor(s2, m, 64);
            }
            sv[fr][j] = s; s2v[fr][j] = s2;
        }

    if (li == 0) {
#pragma unroll
        for (int fr = 0; fr < 2; fr++)
#pragma unroll
            for (int j = 0; j < 4; j++) {
                int row64 = wr * 32 + fr * 16 + lo4 * 4 + j;
                ps[wc][row64]  = sv[fr][j];
                ps2[wc][row64] = s2v[fr][j];
            }
    }
    __syncthreads();

#pragma unroll
    for (int fr = 0; fr < 2; fr++)
#pragma unroll
        for (int j = 0; j < 4; j++) {
            int row64 = wr * 32 + fr * 16 + lo4 * 4 + j;
            int gr = brow + row64;
            float s  = sv[fr][j]  + ps[1 - wc][row64];
            float s2 = s2v[fr][j] + ps2[1 - wc][row64];
            float mean = s * (1.0f / 128.0f);
            float var  = s2 * (1.0f / 128.0f) - mean * mean;
            float rstd = rsqrtf(var + 1e-5f);
            if (gr < M) {
#pragma unroll
                for (int fc = 0; fc < 4; fc++) {
                    int col = wc * 64 + fc * 16 + li;
                    float o = (acc[fr][fc][j] - mean) * rstd * g8[fc] + be8[fc];
                    if (OUT_BF16) Cb[(size_t)gr * 128 + col] = f2b(o);
                    else          Cf[(size_t)gr * 128 + col] = o;
                }
            }
        }
}

// ---------------------------------------------------------------------------
extern "C" void kernel_launch(void* const* d_in, const int* in_sizes, int n_in,
                              void* d_out, int out_size, void* d_ws, size_t ws_size,
                              hipStream_t stream)
{
    const float* x    = (const float*)d_in[0];
    const int*   ei   = (const int*)d_in[1];
    const float* ea   = (const float*)d_in[2];
    const float* Wn1  = (const float*)d_in[3];
    const float* bn1  = (const float*)d_in[4];
    const float* We1  = (const float*)d_in[5];
    const float* be1  = (const float*)d_in[6];
    const float* Wu1  = (const float*)d_in[7];
    const float* bu1  = (const float*)d_in[8];
    const float* g1   = (const float*)d_in[9];
    const float* beta1= (const float*)d_in[10];
    const float* Wn2  = (const float*)d_in[11];
    const float* bn2  = (const float*)d_in[12];
    const float* We2  = (const float*)d_in[13];
    const float* be2  = (const float*)d_in[14];
    const float* Wu2  = (const float*)d_in[15];
    const float* bu2  = (const float*)d_in[16];
    const float* g2   = (const float*)d_in[17];
    const float* beta2= (const float*)d_in[18];

    const int* srcI = ei;
    const int* dstI = ei + NE;
    float* out = (float*)d_out;

    // ---- workspace layout (round-10)
    float* invc = (float*)d_ws;                        // N
    int*   rp   = (int*)(invc + NN);                   // N+1
    int*   hist = rp + NN + 1;                         // N
    int*   psum = hist + NN;                           // 256
    uintptr_t pbase = ((uintptr_t)(psum + 256) + 7) & ~(uintptr_t)7;
    int2*  pairs = (int2*)pbase;                       // E (8B each)
    uintptr_t base = ((uintptr_t)(pairs + NE) + 15) & ~(uintptr_t)15;
    ushort* Xb    = (ushort*)base;                     // N*128 bf16 (also h1)
    ushort* meanb = Xb + (size_t)NN * 128;             // N*128
    ushort* aggEb = meanb + (size_t)NN * 128;          // N*32
    ushort* Btp1  = aggEb + (size_t)NN * 32;           // 36*128*8
    ushort* Btp2  = Btp1 + NOCT * 1024;
    float*  r1    = (float*)(Btp2 + NOCT * 1024);      // 128
    float*  r2    = r1 + 128;

    const int gemm_grid = (NN + 63) / 64;

    // ---- setup: zero hist, then merged prep1|prep2|castx|hist
    hipMemsetAsync(hist, 0, NN * sizeof(int), stream);
    init_kernel<<<CASTX_BLOCKS + HIST_BLOCKS + 2 * PREP_BLOCKS, 256, 0, stream>>>(
        x, Xb, dstI, hist,
        Wn1, bn1, We1, be1, Wu1, Btp1, r1,
        Wn2, bn2, We2, be2, Wu2, Btp2, r2);

    // ---- CSR build
    scan1_kernel<<<NBLK, 256, 0, stream>>>(hist, rp, psum);
    scan23_kernel<<<NBLK, 256, 0, stream>>>(rp, psum);
    place_kernel<<<2048, 256, 0, stream>>>(srcI, dstI, rp, hist, pairs, NE);

    // ---- layer 1 (computes meanb + layer-invariant aggEb/invc)
    agg_kernel<true><<<(NN + 3) / 4, 256, 0, stream>>>(Xb, ea, pairs, rp,
                                                       meanb, aggEb, invc);
    gemmF_kernel<true><<<gemm_grid, 256, 0, stream>>>(
        Xb, meanb, aggEb, invc, Btp1, r1, bu1, g1, beta1, nullptr, Xb, NN);

    // ---- layer 2 (Xb now holds h1 bf16; aggEb/invc reused)
    agg_kernel<false><<<(NN + 3) / 4, 256, 0, stream>>>(Xb, ea, pairs, rp,
                                                        meanb, aggEb, invc);
    gemmF_kernel<false><<<gemm_grid, 256, 0, stream>>>(
        Xb, meanb, aggEb, invc, Btp2, r2, bu2, g2, beta2, out, nullptr, NN);
}

// Round 14
// 274.636 us; speedup vs baseline: 1.1519x; 1.0158x over previous
//
#include <hip/hip_runtime.h>

constexpr int NN = 100000;
constexpr int NE = 800000;
constexpr int SCAN_CHUNK = 512;
constexpr int NBLK = (NN + SCAN_CHUNK - 1) / SCAN_CHUNK;   // 196
constexpr int KTOT = 288;          // 128 (x) + 128 (mean) + 32 (aggE)
constexpr int NOCT = KTOT / 8;     // 36 k-octets

constexpr int CASTX_BLOCKS = (NN * 128 / 8 + 255) / 256;   // 6250
constexpr int HIST_BLOCKS  = 2048;
constexpr int PREP_BLOCKS  = (KTOT * 128 + 128 + 255) / 256; // 145

typedef short bf16x8 __attribute__((ext_vector_type(8)));
typedef float f32x4  __attribute__((ext_vector_type(4)));

__device__ inline ushort f2b(float f) {
    uint u = __builtin_bit_cast(uint, f);
    u += 0x7FFF + ((u >> 16) & 1);
    return (ushort)(u >> 16);
}
__device__ inline float b2f(ushort h) {
    uint u = (uint)h << 16;
    return __builtin_bit_cast(float, u);
}

// async global->LDS DMA, 16B per lane; lds dest = wave-uniform base + lane*16
__device__ inline void gload16(const void* g, void* l) {
    __builtin_amdgcn_global_load_lds(
        (const __attribute__((address_space(1))) void*)g,
        (__attribute__((address_space(3))) void*)l, 16, 0, 0);
}

// ---------------------------------------------------------------------------
// prep body: Btp[NOCT][128][8] bf16 (pre-transposed B) + r vector
__device__ inline void prep_body(int i, const float* __restrict__ Wn,
                                 const float* __restrict__ bn,
                                 const float* __restrict__ We,
                                 const float* __restrict__ be,
                                 const float* __restrict__ Wu,
                                 ushort* __restrict__ Btp, float* __restrict__ r) {
    if (i < KTOT * 128) {
        int K = i >> 7, col = i & 127;
        float v;
        if (K < 128) {
            v = Wu[(size_t)K * 128 + col];
        } else if (K < 256) {
            const float* Wubot = Wu + 128 * 128;
            float s = 0.f;
            for (int m = 0; m < 128; m++)
                s = fmaf(Wn[(K - 128) * 128 + m], Wubot[m * 128 + col], s);
            v = s;
        } else {
            const float* Wubot = Wu + 128 * 128;
            float s = 0.f;
            for (int m = 0; m < 128; m++)
                s = fmaf(We[(K - 256) * 128 + m], Wubot[m * 128 + col], s);
            v = s;
        }
        Btp[(size_t)(K >> 3) * 1024 + col * 8 + (K & 7)] = f2b(v);
    } else if (i < KTOT * 128 + 128) {
        int col = i - KTOT * 128;
        const float* Wubot = Wu + 128 * 128;
        float s = 0.f;
        for (int m = 0; m < 128; m++)
            s = fmaf(bn[m] + be[m], Wubot[m * 128 + col], s);
        r[col] = s;
    }
}

// ---------------------------------------------------------------------------
// merged setup: prep1 | prep2 | castx | hist
__global__ __launch_bounds__(256)
void init_kernel(const float* __restrict__ x, ushort* __restrict__ Xb,
                 const int* __restrict__ dst, int* __restrict__ hist,
                 const float* __restrict__ Wn1, const float* __restrict__ bn1,
                 const float* __restrict__ We1, const float* __restrict__ be1,
                 const float* __restrict__ Wu1,
                 ushort* __restrict__ Btp1, float* __restrict__ r1,
                 const float* __restrict__ Wn2, const float* __restrict__ bn2,
                 const float* __restrict__ We2, const float* __restrict__ be2,
                 const float* __restrict__ Wu2,
                 ushort* __restrict__ Btp2, float* __restrict__ r2) {
    int b = blockIdx.x;
    if (b < PREP_BLOCKS) {
        int i = b * 256 + threadIdx.x;
        prep_body(i, Wn1, bn1, We1, be1, Wu1, Btp1, r1);
    } else if (b < 2 * PREP_BLOCKS) {
        int i = (b - PREP_BLOCKS) * 256 + threadIdx.x;
        prep_body(i, Wn2, bn2, We2, be2, Wu2, Btp2, r2);
    } else if (b < 2 * PREP_BLOCKS + CASTX_BLOCKS) {
        size_t i = ((size_t)(b - 2 * PREP_BLOCKS) * 256 + threadIdx.x) * 8;
        if (i >= (size_t)NN * 128) return;
        float4 v0 = *reinterpret_cast<const float4*>(&x[i]);
        float4 v1 = *reinterpret_cast<const float4*>(&x[i + 4]);
        ushort o[8] = {f2b(v0.x), f2b(v0.y), f2b(v0.z), f2b(v0.w),
                       f2b(v1.x), f2b(v1.y), f2b(v1.z), f2b(v1.w)};
        *reinterpret_cast<bf16x8*>(&Xb[i]) = *reinterpret_cast<bf16x8*>(o);
    } else {
        int bb = b - 2 * PREP_BLOCKS - CASTX_BLOCKS;
        for (int i = bb * 256 + threadIdx.x; i < NE; i += HIST_BLOCKS * 256)
            atomicAdd(&hist[dst[i]], 1);
    }
}

// ---------------------------------------------------------------------------
// scan1: per-chunk exclusive scan + chunk totals
__global__ __launch_bounds__(256)
void scan1_kernel(const int* __restrict__ hist, int* __restrict__ rp,
                  int* __restrict__ psum) {
    __shared__ int wsum[4];
    const int b = blockIdx.x, t = threadIdx.x;
    const int i0 = b * SCAN_CHUNK + 2 * t;
    int v0 = (i0     < NN) ? hist[i0]     : 0;
    int v1 = (i0 + 1 < NN) ? hist[i0 + 1] : 0;
    const int ts = v0 + v1;
    const int lane = t & 63, wid = t >> 6;
    int x = ts;
#pragma unroll
    for (int d = 1; d < 64; d <<= 1) {
        int n = __shfl_up(x, d, 64);
        if (lane >= d) x += n;
    }
    if (lane == 63) wsum[wid] = x;
    __syncthreads();
    int woff = (wid > 0 ? wsum[0] : 0) + (wid > 1 ? wsum[1] : 0) +
               (wid > 2 ? wsum[2] : 0);
    int incl = x + woff;
    int excl = incl - ts;
    if (i0     < NN) rp[i0]     = excl;
    if (i0 + 1 < NN) rp[i0 + 1] = excl + v0;
    if (t == 255) psum[b] = incl;
}

// scan2+3 merged
__global__ __launch_bounds__(256)
void scan23_kernel(int* __restrict__ rp, const int* __restrict__ psum) {
    __shared__ int wred[4];
    const int b = blockIdx.x, t = threadIdx.x;
    int val = (t < b) ? psum[t] : 0;    // b <= NBLK-1 < 256
    const int lane = t & 63, wid = t >> 6;
#pragma unroll
    for (int m = 1; m < 64; m <<= 1) val += __shfl_xor(val, m, 64);
    if (lane == 0) wred[wid] = val;
    __syncthreads();
    const int off = wred[0] + wred[1] + wred[2] + wred[3];
    const int i0 = b * SCAN_CHUNK + 2 * t;
    if (i0     < NN) rp[i0]     += off;
    if (i0 + 1 < NN) rp[i0 + 1] += off;
    if (b == 0 && t == 0) rp[NN] = NE;
}

// ---------------------------------------------------------------------------
// placement; hist counted DOWN to zero; ONE packed 8B write per edge
__global__ __launch_bounds__(256)
void place_kernel(const int* __restrict__ src, const int* __restrict__ dst,
                  const int* __restrict__ rp, int* __restrict__ hist,
                  int2* __restrict__ pairs, int E) {
    for (int e = blockIdx.x * blockDim.x + threadIdx.x; e < E;
         e += gridDim.x * blockDim.x) {
        int d = dst[e];
        int pos = rp[d] + atomicSub(&hist[d], 1) - 1;
        pairs[pos] = make_int2(src[e], e);
    }
}

// ---------------------------------------------------------------------------
// CSR aggregation, edge-pair scheme (round-10 measured-best, unchanged)
template<bool DO_EA>
__global__ __launch_bounds__(256)
void agg_kernel(const ushort* __restrict__ Xb, const float* __restrict__ ea,
                const int2* __restrict__ pairs, const int* __restrict__ rp,
                ushort* __restrict__ meanb, ushort* __restrict__ aggEb,
                float* __restrict__ invc) {
    const int wid  = __builtin_amdgcn_readfirstlane(threadIdx.x >> 6);
    const int lane = threadIdx.x & 63;
    const int v = blockIdx.x * 4 + wid;
    if (v >= NN) return;
    const int beg = __builtin_amdgcn_readfirstlane(rp[v]);
    const int end = __builtin_amdgcn_readfirstlane(rp[v + 1]);
    const int half = lane >> 5;
    const int l32  = lane & 31;

    float a0 = 0.f, a1 = 0.f, a2 = 0.f, a3 = 0.f;
    float aE = 0.f;
    int i = beg;
    for (; i + 7 < end; i += 8) {
        int2 p0 = pairs[i],     p1 = pairs[i + 1];
        int2 p2 = pairs[i + 2], p3 = pairs[i + 3];
        int2 p4 = pairs[i + 4], p5 = pairs[i + 5];
        int2 p6 = pairs[i + 6], p7 = pairs[i + 7];
        int s0 = __builtin_amdgcn_readfirstlane(p0.x);
        int s1 = __builtin_amdgcn_readfirstlane(p1.x);
        int s2 = __builtin_amdgcn_readfirstlane(p2.x);
        int s3 = __builtin_amdgcn_readfirstlane(p3.x);
        int s4 = __builtin_amdgcn_readfirstlane(p4.x);
        int s5 = __builtin_amdgcn_readfirstlane(p5.x);
        int s6 = __builtin_amdgcn_readfirstlane(p6.x);
        int s7 = __builtin_amdgcn_readfirstlane(p7.x);
        int sA = half ? s1 : s0, sB = half ? s3 : s2;
        int sC = half ? s5 : s4, sD = half ? s7 : s6;
        uint2 qA = *reinterpret_cast<const uint2*>(Xb + (size_t)sA * 128 + l32 * 4);
        uint2 qB = *reinterpret_cast<const uint2*>(Xb + (size_t)sB * 128 + l32 * 4);
        uint2 qC = *reinterpret_cast<const uint2*>(Xb + (size_t)sC * 128 + l32 * 4);
        uint2 qD = *reinterpret_cast<const uint2*>(Xb + (size_t)sD * 128 + l32 * 4);
        if (DO_EA) {
            int e0 = __builtin_amdgcn_readfirstlane(p0.y);
            int e1 = __builtin_amdgcn_readfirstlane(p1.y);
            int e2 = __builtin_amdgcn_readfirstlane(p2.y);
            int e3 = __builtin_amdgcn_readfirstlane(p3.y);
            int e4 = __builtin_amdgcn_readfirstlane(p4.y);
            int e5 = __builtin_amdgcn_readfirstlane(p5.y);
            int e6 = __builtin_amdgcn_readfirstlane(p6.y);
            int e7 = __builtin_amdgcn_readfirstlane(p7.y);
            int eA = half ? e1 : e0, eB = half ? e3 : e2;
            int eC = half ? e5 : e4, eD = half ? e7 : e6;
            float fA = ea[(size_t)eA * 32 + l32];
            float fB = ea[(size_t)eB * 32 + l32];
            float fC = ea[(size_t)eC * 32 + l32];
            float fD = ea[(size_t)eD * 32 + l32];
            aE += (fA + fB) + (fC + fD);
        }
        a0 += (b2f((ushort)qA.x) + b2f((ushort)qB.x)) +
              (b2f((ushort)qC.x) + b2f((ushort)qD.x));
        a1 += (b2f((ushort)(qA.x >> 16)) + b2f((ushort)(qB.x >> 16))) +
              (b2f((ushort)(qC.x >> 16)) + b2f((ushort)(qD.x >> 16)));
        a2 += (b2f((ushort)qA.y) + b2f((ushort)qB.y)) +
              (b2f((ushort)qC.y) + b2f((ushort)qD.y));
        a3 += (b2f((ushort)(qA.y >> 16)) + b2f((ushort)(qB.y >> 16))) +
              (b2f((ushort)(qC.y >> 16)) + b2f((ushort)(qD.y >> 16)));
    }
    if (i + 3 < end) {
        int2 p0 = pairs[i],     p1 = pairs[i + 1];
        int2 p2 = pairs[i + 2], p3 = pairs[i + 3];
        int s0 = __builtin_amdgcn_readfirstlane(p0.x);
        int s1 = __builtin_amdgcn_readfirstlane(p1.x);
        int s2 = __builtin_amdgcn_readfirstlane(p2.x);
        int s3 = __builtin_amdgcn_readfirstlane(p3.x);
        int sA = half ? s1 : s0, sB = half ? s3 : s2;
        uint2 qA = *reinterpret_cast<const uint2*>(Xb + (size_t)sA * 128 + l32 * 4);
        uint2 qB = *reinterpret_cast<const uint2*>(Xb + (size_t)sB * 128 + l32 * 4);
        if (DO_EA) {
            int e0 = __builtin_amdgcn_readfirstlane(p0.y);
            int e1 = __builtin_amdgcn_readfirstlane(p1.y);
            int e2 = __builtin_amdgcn_readfirstlane(p2.y);
            int e3 = __builtin_amdgcn_readfirstlane(p3.y);
            int eA = half ? e1 : e0, eB = half ? e3 : e2;
            aE += ea[(size_t)eA * 32 + l32] + ea[(size_t)eB * 32 + l32];
        }
        a0 += b2f((ushort)qA.x) + b2f((ushort)qB.x);
        a1 += b2f((ushort)(qA.x >> 16)) + b2f((ushort)(qB.x >> 16));
        a2 += b2f((ushort)qA.y) + b2f((ushort)qB.y);
        a3 += b2f((ushort)(qA.y >> 16)) + b2f((ushort)(qB.y >> 16));
        i += 4;
    }
    if (i + 1 < end) {
        int2 p0 = pairs[i], p1 = pairs[i + 1];
        int s0 = __builtin_amdgcn_readfirstlane(p0.x);
        int s1 = __builtin_amdgcn_readfirstlane(p1.x);
        int sA = half ? s1 : s0;
        uint2 qA = *reinterpret_cast<const uint2*>(Xb + (size_t)sA * 128 + l32 * 4);
        if (DO_EA) {
            int e0 = __builtin_amdgcn_readfirstlane(p0.y);
            int e1 = __builtin_amdgcn_readfirstlane(p1.y);
            int eA = half ? e1 : e0;
            aE += ea[(size_t)eA * 32 + l32];
        }
        a0 += b2f((ushort)qA.x);
        a1 += b2f((ushort)(qA.x >> 16));
        a2 += b2f((ushort)qA.y);
        a3 += b2f((ushort)(qA.y >> 16));
        i += 2;
    }
    if (i < end) {
        int2 p0 = pairs[i];
        int s0 = __builtin_amdgcn_readfirstlane(p0.x);
        if (half == 0) {
            uint2 qA = *reinterpret_cast<const uint2*>(Xb + (size_t)s0 * 128 + l32 * 4);
            a0 += b2f((ushort)qA.x);
            a1 += b2f((ushort)(qA.x >> 16));
            a2 += b2f((ushort)qA.y);
            a3 += b2f((ushort)(qA.y >> 16));
            if (DO_EA) {
                int e0 = __builtin_amdgcn_readfirstlane(p0.y);
                aE += ea[(size_t)e0 * 32 + l32];
            }
        }
    }
    a0 += __shfl_xor(a0, 32, 64);
    a1 += __shfl_xor(a1, 32, 64);
    a2 += __shfl_xor(a2, 32, 64);
    a3 += __shfl_xor(a3, 32, 64);
    if (DO_EA) aE += __shfl_xor(aE, 32, 64);

    float inv = (end > beg) ? 1.0f / (float)(end - beg) : 0.0f;
    if (half == 0) {
        uint lo = (uint)f2b(a0 * inv) | ((uint)f2b(a1 * inv) << 16);
        uint hi = (uint)f2b(a2 * inv) | ((uint)f2b(a3 * inv) << 16);
        *reinterpret_cast<uint2*>(meanb + (size_t)v * 128 + l32 * 4) =
            make_uint2(lo, hi);
        if (DO_EA) aggEb[(size_t)v * 32 + l32] = f2b(aE * inv);
    }
    if (DO_EA && lane == 0) invc[v] = inv;
}

// ---------------------------------------------------------------------------
// fused MFMA GEMM, 64-row tile; DOUBLE-BUFFERED gload16 staging with counted
// vmcnt (never 0 in main loop) + raw s_barrier (m201 discipline).
// Per step per wave: 3 DMA issues (1 A + 2 B). vmcnt(3) retires the current
// buffer's 3 (FIFO), leaving next buffer's 3 in flight across the MFMA phase.
template<bool OUT_BF16>
__global__ __launch_bounds__(256)
void gemmF_kernel(const ushort* __restrict__ Xb, const ushort* __restrict__ meanb,
                  const ushort* __restrict__ aggEb, const float* __restrict__ invc,
                  const ushort* __restrict__ Btp, const float* __restrict__ r,
                  const float* __restrict__ bu, const float* __restrict__ g,
                  const float* __restrict__ beta,
                  float* __restrict__ Cf, ushort* __restrict__ Cb, int M) {
    __shared__ __align__(16) ushort Als[2][4][64][8];    // 8 KB
    __shared__ __align__(16) ushort Bls[2][4][128][8];   // 16 KB
    __shared__ float ps[2][64], ps2[2][64];

    const int tid = threadIdx.x;
    const int wid = tid >> 6, lane = tid & 63;
    const int wr = wid >> 1, wc = wid & 1;
    const int lo4 = lane >> 4, li = lane & 15;
    const int brow = blockIdx.x * 64;

    f32x4 acc[2][4];
#pragma unroll
    for (int fr = 0; fr < 2; fr++)
#pragma unroll
        for (int fc = 0; fc < 4; fc++) acc[fr][fc] = (f32x4)0.f;

    const int akc  = wid;               // wave id = staged k-octet
    const int grow = brow + lane;       // per-lane A row

    // stage step `st` into buffer `bf`: 3 DMA issues per wave
    auto stage = [&](int bf, int st) {
        int kg = st * 4 + akc;          // wave-uniform
        const ushort* gA;
        if (kg < 16)      gA = Xb    + (size_t)grow * 128 + kg * 8;
        else if (kg < 32) gA = meanb + (size_t)grow * 128 + (kg - 16) * 8;
        else              gA = aggEb + (size_t)grow * 32  + (kg - 32) * 8;
        gload16(gA, &Als[bf][akc][0][0]);
#pragma unroll
        for (int h = 0; h < 2; h++) {
            int ub = h * 256 + akc * 64;
            gload16(Btp + ((size_t)st * 512 + ub + lane) * 8,
                    &Bls[bf][0][0][0] + (size_t)ub * 8);
        }
    };

    stage(0, 0);
    int cur = 0;
    for (int step = 0; step < 9; step++) {
        if (step < 8) {
            stage(cur ^ 1, step + 1);
            asm volatile("s_waitcnt vmcnt(3)" ::: "memory");
        } else {
            asm volatile("s_waitcnt vmcnt(0)" ::: "memory");
        }
        __builtin_amdgcn_sched_barrier(0);
        __builtin_amdgcn_s_barrier();       // all waves' cur-buffer DMAs done

        bf16x8 a0 = *reinterpret_cast<const bf16x8*>(&Als[cur][lo4][wr * 32 + li][0]);
        bf16x8 a1 = *reinterpret_cast<const bf16x8*>(&Als[cur][lo4][wr * 32 + 16 + li][0]);
#pragma unroll
        for (int fc = 0; fc < 4; fc++) {
            bf16x8 b = *reinterpret_cast<const bf16x8*>(&Bls[cur][lo4][wc * 64 + fc * 16 + li][0]);
            acc[0][fc] = __builtin_amdgcn_mfma_f32_16x16x32_bf16(a0, b, acc[0][fc], 0, 0, 0);
            acc[1][fc] = __builtin_amdgcn_mfma_f32_16x16x32_bf16(a1, b, acc[1][fc], 0, 0, 0);
        }
        __builtin_amdgcn_s_barrier();       // reads of cur done before restage
        cur ^= 1;
    }

    float bu8[4], r8[4], g8[4], be8[4];
#pragma unroll
    for (int fc = 0; fc < 4; fc++) {
        int col = wc * 64 + fc * 16 + li;
        bu8[fc] = bu[col]; r8[fc] = r[col]; g8[fc] = g[col]; be8[fc] = beta[col];
    }

    float sv[2][4], s2v[2][4];
#pragma unroll
    for (int fr = 0; fr < 2; fr++)
#pragma unroll
        for (int j = 0; j < 4; j++) {
            int gr = brow + wr * 32 + fr * 16 + lo4 * 4 + j;
            float hv = 0.f;
            if (gr < M) hv = (invc[gr] > 0.f) ? 1.f : 0.f;
            float s = 0.f, s2 = 0.f;
#pragma unroll
            for (int fc = 0; fc < 4; fc++) {
                float val = acc[fr][fc][j] + bu8[fc] + hv * r8[fc];
                val = fmaxf(val, 0.f);
                acc[fr][fc][j] = val;
                s += val; s2 += val * val;
            }
#pragma unroll
            for (int m = 1; m < 16; m <<= 1) {
                s  += __shfl_xor(s, m, 64);
                s2 += __shfl_xor(s2, m, 64);
            }
            sv[fr][j] = s; s2v[fr][j] = s2;
        }

    if (li == 0) {
#pragma unroll
        for (int fr = 0; fr < 2; fr++)
#pragma unroll
            for (int j = 0; j < 4; j++) {
                int row64 = wr * 32 + fr * 16 + lo4 * 4 + j;
                ps[wc][row64]  = sv[fr][j];
                ps2[wc][row64] = s2v[fr][j];
            }
    }
    __syncthreads();

#pragma unroll
    for (int fr = 0; fr < 2; fr++)
#pragma unroll
        for (int j = 0; j < 4; j++) {
            int row64 = wr * 32 + fr * 16 + lo4 * 4 + j;
            int gr = brow + row64;
            float s  = sv[fr][j]  + ps[1 - wc][row64];
            float s2 = s2v[fr][j] + ps2[1 - wc][row64];
            float mean = s * (1.0f / 128.0f);
            float var  = s2 * (1.0f / 128.0f) - mean * mean;
            float rstd = rsqrtf(var + 1e-5f);
            if (gr < M) {
#pragma unroll
                for (int fc = 0; fc < 4; fc++) {
                    int col = wc * 64 + fc * 16 + li;
                    float o = (acc[fr][fc][j] - mean) * rstd * g8[fc] + be8[fc];
                    if (OUT_BF16) Cb[(size_t)gr * 128 + col] = f2b(o);
                    else          Cf[(size_t)gr * 128 + col] = o;
                }
            }
        }
}

// ---------------------------------------------------------------------------
extern "C" void kernel_launch(void* const* d_in, const int* in_sizes, int n_in,
                              void* d_out, int out_size, void* d_ws, size_t ws_size,
                              hipStream_t stream)
{
    const float* x    = (const float*)d_in[0];
    const int*   ei   = (const int*)d_in[1];
    const float* ea   = (const float*)d_in[2];
    const float* Wn1  = (const float*)d_in[3];
    const float* bn1  = (const float*)d_in[4];
    const float* We1  = (const float*)d_in[5];
    const float* be1  = (const float*)d_in[6];
    const float* Wu1  = (const float*)d_in[7];
    const float* bu1  = (const float*)d_in[8];
    const float* g1   = (const float*)d_in[9];
    const float* beta1= (const float*)d_in[10];
    const float* Wn2  = (const float*)d_in[11];
    const float* bn2  = (const float*)d_in[12];
    const float* We2  = (const float*)d_in[13];
    const float* be2  = (const float*)d_in[14];
    const float* Wu2  = (const float*)d_in[15];
    const float* bu2  = (const float*)d_in[16];
    const float* g2   = (const float*)d_in[17];
    const float* beta2= (const float*)d_in[18];

    const int* srcI = ei;
    const int* dstI = ei + NE;
    float* out = (float*)d_out;

    // ---- workspace layout (round-10)
    float* invc = (float*)d_ws;                        // N
    int*   rp   = (int*)(invc + NN);                   // N+1
    int*   hist = rp + NN + 1;                         // N
    int*   psum = hist + NN;                           // 256
    uintptr_t pbase = ((uintptr_t)(psum + 256) + 7) & ~(uintptr_t)7;
    int2*  pairs = (int2*)pbase;                       // E (8B each)
    uintptr_t base = ((uintptr_t)(pairs + NE) + 15) & ~(uintptr_t)15;
    ushort* Xb    = (ushort*)base;                     // N*128 bf16 (also h1)
    ushort* meanb = Xb + (size_t)NN * 128;             // N*128
    ushort* aggEb = meanb + (size_t)NN * 128;          // N*32
    ushort* Btp1  = aggEb + (size_t)NN * 32;           // 36*128*8
    ushort* Btp2  = Btp1 + NOCT * 1024;
    float*  r1    = (float*)(Btp2 + NOCT * 1024);      // 128
    float*  r2    = r1 + 128;

    const int gemm_grid = (NN + 63) / 64;

    // ---- setup: zero hist, then merged prep1|prep2|castx|hist
    hipMemsetAsync(hist, 0, NN * sizeof(int), stream);
    init_kernel<<<CASTX_BLOCKS + HIST_BLOCKS + 2 * PREP_BLOCKS, 256, 0, stream>>>(
        x, Xb, dstI, hist,
        Wn1, bn1, We1, be1, Wu1, Btp1, r1,
        Wn2, bn2, We2, be2, Wu2, Btp2, r2);

    // ---- CSR build
    scan1_kernel<<<NBLK, 256, 0, stream>>>(hist, rp, psum);
    scan23_kernel<<<NBLK, 256, 0, stream>>>(rp, psum);
    place_kernel<<<2048, 256, 0, stream>>>(srcI, dstI, rp, hist, pairs, NE);

    // ---- layer 1 (computes meanb + layer-invariant aggEb/invc)
    agg_kernel<true><<<(NN + 3) / 4, 256, 0, stream>>>(Xb, ea, pairs, rp,
                                                       meanb, aggEb, invc);
    gemmF_kernel<true><<<gemm_grid, 256, 0, stream>>>(
        Xb, meanb, aggEb, invc, Btp1, r1, bu1, g1, beta1, nullptr, Xb, NN);

    // ---- layer 2 (Xb now holds h1 bf16; aggEb/invc reused)
    agg_kernel<false><<<(NN + 3) / 4, 256, 0, stream>>>(Xb, ea, pairs, rp,
                                                        meanb, aggEb, invc);
    gemmF_kernel<false><<<gemm_grid, 256, 0, stream>>>(
        Xb, meanb, aggEb, invc, Btp2, r2, bu2, g2, beta2, out, nullptr, NN);
}

// Round 15
// 272.004 us; speedup vs baseline: 1.1631x; 1.0097x over previous
//
#include <hip/hip_runtime.h>

constexpr int NN = 100000;
constexpr int NE = 800000;
constexpr int SCAN_CHUNK = 512;
constexpr int NBLK = (NN + SCAN_CHUNK - 1) / SCAN_CHUNK;   // 196
constexpr int KTOT = 288;          // 128 (x) + 128 (mean) + 32 (aggE)
constexpr int NOCT = KTOT / 8;     // 36 k-octets

constexpr int CASTQ_BLOCKS = (NN + 7) / 8;                 // 12500 (8 rows/block)
constexpr int HIST_BLOCKS  = 2048;
constexpr int PREP_BLOCKS  = (KTOT * 128 + 128 + 255) / 256; // 145

typedef short bf16x8 __attribute__((ext_vector_type(8)));
typedef float f32x4  __attribute__((ext_vector_type(4)));

__device__ inline ushort f2b(float f) {
    uint u = __builtin_bit_cast(uint, f);
    u += 0x7FFF + ((u >> 16) & 1);
    return (ushort)(u >> 16);
}
__device__ inline float b2f(ushort h) {
    uint u = (uint)h << 16;
    return __builtin_bit_cast(float, u);
}

// async global->LDS DMA, 16B per lane; lds dest = wave-uniform base + lane*16
__device__ inline void gload16(const void* g, void* l) {
    __builtin_amdgcn_global_load_lds(
        (const __attribute__((address_space(1))) void*)g,
        (__attribute__((address_space(3))) void*)l, 16, 0, 0);
}

// ---------------------------------------------------------------------------
// prep body: Btp[NOCT][128][8] bf16 (pre-transposed B) + r vector
__device__ inline void prep_body(int i, const float* __restrict__ Wn,
                                 const float* __restrict__ bn,
                                 const float* __restrict__ We,
                                 const float* __restrict__ be,
                                 const float* __restrict__ Wu,
                                 ushort* __restrict__ Btp, float* __restrict__ r) {
    if (i < KTOT * 128) {
        int K = i >> 7, col = i & 127;
        float v;
        if (K < 128) {
            v = Wu[(size_t)K * 128 + col];
        } else if (K < 256) {
            const float* Wubot = Wu + 128 * 128;
            float s = 0.f;
            for (int m = 0; m < 128; m++)
                s = fmaf(Wn[(K - 128) * 128 + m], Wubot[m * 128 + col], s);
            v = s;
        } else {
            const float* Wubot = Wu + 128 * 128;
            float s = 0.f;
            for (int m = 0; m < 128; m++)
                s = fmaf(We[(K - 256) * 128 + m], Wubot[m * 128 + col], s);
            v = s;
        }
        Btp[(size_t)(K >> 3) * 1024 + col * 8 + (K & 7)] = f2b(v);
    } else if (i < KTOT * 128 + 128) {
        int col = i - KTOT * 128;
        const float* Wubot = Wu + 128 * 128;
        float s = 0.f;
        for (int m = 0; m < 128; m++)
            s = fmaf(bn[m] + be[m], Wubot[m * 128 + col], s);
        r[col] = s;
    }
}

// ---------------------------------------------------------------------------
// merged setup: prep1 | prep2 | castq | hist
// castq: per row -> bf16 row (GEMM operand) + int8 row + scale (gather table)
__global__ __launch_bounds__(256)
void init_kernel(const float* __restrict__ x, ushort* __restrict__ Xb,
                 uint* __restrict__ Xq32, float* __restrict__ sc,
                 const int* __restrict__ dst, int* __restrict__ hist,
                 const float* __restrict__ Wn1, const float* __restrict__ bn1,
                 const float* __restrict__ We1, const float* __restrict__ be1,
                 const float* __restrict__ Wu1,
                 ushort* __restrict__ Btp1, float* __restrict__ r1,
                 const float* __restrict__ Wn2, const float* __restrict__ bn2,
                 const float* __restrict__ We2, const float* __restrict__ be2,
                 const float* __restrict__ Wu2,
                 ushort* __restrict__ Btp2, float* __restrict__ r2) {
    int b = blockIdx.x;
    if (b < PREP_BLOCKS) {
        int i = b * 256 + threadIdx.x;
        prep_body(i, Wn1, bn1, We1, be1, Wu1, Btp1, r1);
    } else if (b < 2 * PREP_BLOCKS) {
        int i = (b - PREP_BLOCKS) * 256 + threadIdx.x;
        prep_body(i, Wn2, bn2, We2, be2, Wu2, Btp2, r2);
    } else if (b < 2 * PREP_BLOCKS + CASTQ_BLOCKS) {
        int bb = b - 2 * PREP_BLOCKS;
        int w = threadIdx.x >> 6, lane = threadIdx.x & 63;
        int row = bb * 8 + w * 2 + (lane >> 5);
        int l32 = lane & 31;
        if (row >= NN) return;
        float4 v = *reinterpret_cast<const float4*>(&x[(size_t)row * 128 + l32 * 4]);
        // bf16 row
        uint lo = (uint)f2b(v.x) | ((uint)f2b(v.y) << 16);
        uint hi = (uint)f2b(v.z) | ((uint)f2b(v.w) << 16);
        *reinterpret_cast<uint2*>(&Xb[(size_t)row * 128 + l32 * 4]) = make_uint2(lo, hi);
        // row absmax over 32 lanes (stays within the row's 32-lane group)
        float m = fmaxf(fmaxf(fabsf(v.x), fabsf(v.y)), fmaxf(fabsf(v.z), fabsf(v.w)));
#pragma unroll
        for (int d = 1; d < 32; d <<= 1) m = fmaxf(m, __shfl_xor(m, d, 64));
        float senc = (m > 0.f) ? 127.0f / m : 0.f;
        int q0 = (int)rintf(v.x * senc);
        int q1 = (int)rintf(v.y * senc);
        int q2 = (int)rintf(v.z * senc);
        int q3 = (int)rintf(v.w * senc);
        uint qp = (q0 & 0xff) | ((q1 & 0xff) << 8) | ((q2 & 0xff) << 16) |
                  ((uint)(q3 & 0xff) << 24);
        Xq32[(size_t)row * 32 + l32] = qp;
        if (l32 == 0) sc[row] = m * (1.0f / 127.0f);
    } else {
        int bb = b - 2 * PREP_BLOCKS - CASTQ_BLOCKS;
        for (int i = bb * 256 + threadIdx.x; i < NE; i += HIST_BLOCKS * 256)
            atomicAdd(&hist[dst[i]], 1);
    }
}

// ---------------------------------------------------------------------------
__global__ __launch_bounds__(256)
void scan1_kernel(const int* __restrict__ hist, int* __restrict__ rp,
                  int* __restrict__ psum) {
    __shared__ int wsum[4];
    const int b = blockIdx.x, t = threadIdx.x;
    const int i0 = b * SCAN_CHUNK + 2 * t;
    int v0 = (i0     < NN) ? hist[i0]     : 0;
    int v1 = (i0 + 1 < NN) ? hist[i0 + 1] : 0;
    const int ts = v0 + v1;
    const int lane = t & 63, wid = t >> 6;
    int x = ts;
#pragma unroll
    for (int d = 1; d < 64; d <<= 1) {
        int n = __shfl_up(x, d, 64);
        if (lane >= d) x += n;
    }
    if (lane == 63) wsum[wid] = x;
    __syncthreads();
    int woff = (wid > 0 ? wsum[0] : 0) + (wid > 1 ? wsum[1] : 0) +
               (wid > 2 ? wsum[2] : 0);
    int incl = x + woff;
    int excl = incl - ts;
    if (i0     < NN) rp[i0]     = excl;
    if (i0 + 1 < NN) rp[i0 + 1] = excl + v0;
    if (t == 255) psum[b] = incl;
}

__global__ __launch_bounds__(256)
void scan23_kernel(int* __restrict__ rp, const int* __restrict__ psum) {
    __shared__ int wred[4];
    const int b = blockIdx.x, t = threadIdx.x;
    int val = (t < b) ? psum[t] : 0;
    const int lane = t & 63, wid = t >> 6;
#pragma unroll
    for (int m = 1; m < 64; m <<= 1) val += __shfl_xor(val, m, 64);
    if (lane == 0) wred[wid] = val;
    __syncthreads();
    const int off = wred[0] + wred[1] + wred[2] + wred[3];
    const int i0 = b * SCAN_CHUNK + 2 * t;
    if (i0     < NN) rp[i0]     += off;
    if (i0 + 1 < NN) rp[i0 + 1] += off;
    if (b == 0 && t == 0) rp[NN] = NE;
}

__global__ __launch_bounds__(256)
void place_kernel(const int* __restrict__ src, const int* __restrict__ dst,
                  const int* __restrict__ rp, int* __restrict__ hist,
                  int2* __restrict__ pairs, int E) {
    for (int e = blockIdx.x * blockDim.x + threadIdx.x; e < E;
         e += gridDim.x * blockDim.x) {
        int d = dst[e];
        int pos = rp[d] + atomicSub(&hist[d], 1) - 1;
        pairs[pos] = make_int2(src[e], e);
    }
}

// ---------------------------------------------------------------------------
// CSR aggregation over int8 gather table (128B rows + scalar-loaded scales).
// Pair scheme: lanes 0-31 even edge, 32-63 odd; 8 edges/iter (4 dword gathers).
template<bool DO_EA>
__global__ __launch_bounds__(256)
void agg_kernel(const uint* __restrict__ Xq32, const float* __restrict__ sc,
                const float* __restrict__ ea,
                const int2* __restrict__ pairs, const int* __restrict__ rp,
                ushort* __restrict__ meanb, ushort* __restrict__ aggEb,
                float* __restrict__ invc) {
    const int wid  = __builtin_amdgcn_readfirstlane(threadIdx.x >> 6);
    const int lane = threadIdx.x & 63;
    const int v = blockIdx.x * 4 + wid;
    if (v >= NN) return;
    const int beg = __builtin_amdgcn_readfirstlane(rp[v]);
    const int end = __builtin_amdgcn_readfirstlane(rp[v + 1]);
    const int half = lane >> 5;
    const int l32  = lane & 31;

    float a0 = 0.f, a1 = 0.f, a2 = 0.f, a3 = 0.f;
    float aE = 0.f;
    int i = beg;
    for (; i + 7 < end; i += 8) {
        int2 p0 = pairs[i],     p1 = pairs[i + 1];
        int2 p2 = pairs[i + 2], p3 = pairs[i + 3];
        int2 p4 = pairs[i + 4], p5 = pairs[i + 5];
        int2 p6 = pairs[i + 6], p7 = pairs[i + 7];
        int s0 = __builtin_amdgcn_readfirstlane(p0.x);
        int s1 = __builtin_amdgcn_readfirstlane(p1.x);
        int s2 = __builtin_amdgcn_readfirstlane(p2.x);
        int s3 = __builtin_amdgcn_readfirstlane(p3.x);
        int s4 = __builtin_amdgcn_readfirstlane(p4.x);
        int s5 = __builtin_amdgcn_readfirstlane(p5.x);
        int s6 = __builtin_amdgcn_readfirstlane(p6.x);
        int s7 = __builtin_amdgcn_readfirstlane(p7.x);
        // scalar scale loads on uniform indices (constant-cache path)
        float c0 = sc[s0], c1 = sc[s1], c2 = sc[s2], c3 = sc[s3];
        float c4 = sc[s4], c5 = sc[s5], c6 = sc[s6], c7 = sc[s7];
        int sA = half ? s1 : s0, sB = half ? s3 : s2;
        int sC = half ? s5 : s4, sD = half ? s7 : s6;
        float scA = half ? c1 : c0, scB = half ? c3 : c2;
        float scC = half ? c5 : c4, scD = half ? c7 : c6;
        uint qA = Xq32[(size_t)sA * 32 + l32];
        uint qB = Xq32[(size_t)sB * 32 + l32];
        uint qC = Xq32[(size_t)sC * 32 + l32];
        uint qD = Xq32[(size_t)sD * 32 + l32];
        if (DO_EA) {
            int e0 = __builtin_amdgcn_readfirstlane(p0.y);
            int e1 = __builtin_amdgcn_readfirstlane(p1.y);
            int e2 = __builtin_amdgcn_readfirstlane(p2.y);
            int e3 = __builtin_amdgcn_readfirstlane(p3.y);
            int e4 = __builtin_amdgcn_readfirstlane(p4.y);
            int e5 = __builtin_amdgcn_readfirstlane(p5.y);
            int e6 = __builtin_amdgcn_readfirstlane(p6.y);
            int e7 = __builtin_amdgcn_readfirstlane(p7.y);
            int eA = half ? e1 : e0, eB = half ? e3 : e2;
            int eC = half ? e5 : e4, eD = half ? e7 : e6;
            float fA = ea[(size_t)eA * 32 + l32];
            float fB = ea[(size_t)eB * 32 + l32];
            float fC = ea[(size_t)eC * 32 + l32];
            float fD = ea[(size_t)eD * 32 + l32];
            aE += (fA + fB) + (fC + fD);
        }
        a0 = fmaf((float)(char)qA, scA, a0);
        a1 = fmaf((float)(char)(qA >> 8), scA, a1);
        a2 = fmaf((float)(char)(qA >> 16), scA, a2);
        a3 = fmaf((float)((int)qA >> 24), scA, a3);
        a0 = fmaf((float)(char)qB, scB, a0);
        a1 = fmaf((float)(char)(qB >> 8), scB, a1);
        a2 = fmaf((float)(char)(qB >> 16), scB, a2);
        a3 = fmaf((float)((int)qB >> 24), scB, a3);
        a0 = fmaf((float)(char)qC, scC, a0);
        a1 = fmaf((float)(char)(qC >> 8), scC, a1);
        a2 = fmaf((float)(char)(qC >> 16), scC, a2);
        a3 = fmaf((float)((int)qC >> 24), scC, a3);
        a0 = fmaf((float)(char)qD, scD, a0);
        a1 = fmaf((float)(char)(qD >> 8), scD, a1);
        a2 = fmaf((float)(char)(qD >> 16), scD, a2);
        a3 = fmaf((float)((int)qD >> 24), scD, a3);
    }
    if (i + 3 < end) {
        int2 p0 = pairs[i],     p1 = pairs[i + 1];
        int2 p2 = pairs[i + 2], p3 = pairs[i + 3];
        int s0 = __builtin_amdgcn_readfirstlane(p0.x);
        int s1 = __builtin_amdgcn_readfirstlane(p1.x);
        int s2 = __builtin_amdgcn_readfirstlane(p2.x);
        int s3 = __builtin_amdgcn_readfirstlane(p3.x);
        float c0 = sc[s0], c1 = sc[s1], c2 = sc[s2], c3 = sc[s3];
        int sA = half ? s1 : s0, sB = half ? s3 : s2;
        float scA = half ? c1 : c0, scB = half ? c3 : c2;
        uint qA = Xq32[(size_t)sA * 32 + l32];
        uint qB = Xq32[(size_t)sB * 32 + l32];
        if (DO_EA) {
            int e0 = __builtin_amdgcn_readfirstlane(p0.y);
            int e1 = __builtin_amdgcn_readfirstlane(p1.y);
            int e2 = __builtin_amdgcn_readfirstlane(p2.y);
            int e3 = __builtin_amdgcn_readfirstlane(p3.y);
            int eA = half ? e1 : e0, eB = half ? e3 : e2;
            aE += ea[(size_t)eA * 32 + l32] + ea[(size_t)eB * 32 + l32];
        }
        a0 = fmaf((float)(char)qA, scA, a0);
        a1 = fmaf((float)(char)(qA >> 8), scA, a1);
        a2 = fmaf((float)(char)(qA >> 16), scA, a2);
        a3 = fmaf((float)((int)qA >> 24), scA, a3);
        a0 = fmaf((float)(char)qB, scB, a0);
        a1 = fmaf((float)(char)(qB >> 8), scB, a1);
        a2 = fmaf((float)(char)(qB >> 16), scB, a2);
        a3 = fmaf((float)((int)qB >> 24), scB, a3);
        i += 4;
    }
    if (i + 1 < end) {
        int2 p0 = pairs[i], p1 = pairs[i + 1];
        int s0 = __builtin_amdgcn_readfirstlane(p0.x);
        int s1 = __builtin_amdgcn_readfirstlane(p1.x);
        float c0 = sc[s0], c1 = sc[s1];
        int sA = half ? s1 : s0;
        float scA = half ? c1 : c0;
        uint qA = Xq32[(size_t)sA * 32 + l32];
        if (DO_EA) {
            int e0 = __builtin_amdgcn_readfirstlane(p0.y);
            int e1 = __builtin_amdgcn_readfirstlane(p1.y);
            int eA = half ? e1 : e0;
            aE += ea[(size_t)eA * 32 + l32];
        }
        a0 = fmaf((float)(char)qA, scA, a0);
        a1 = fmaf((float)(char)(qA >> 8), scA, a1);
        a2 = fmaf((float)(char)(qA >> 16), scA, a2);
        a3 = fmaf((float)((int)qA >> 24), scA, a3);
        i += 2;
    }
    if (i < end) {
        int2 p0 = pairs[i];
        int s0 = __builtin_amdgcn_readfirstlane(p0.x);
        float c0 = sc[s0];
        if (half == 0) {
            uint qA = Xq32[(size_t)s0 * 32 + l32];
            a0 = fmaf((float)(char)qA, c0, a0);
            a1 = fmaf((float)(char)(qA >> 8), c0, a1);
            a2 = fmaf((float)(char)(qA >> 16), c0, a2);
            a3 = fmaf((float)((int)qA >> 24), c0, a3);
            if (DO_EA) {
                int e0 = __builtin_amdgcn_readfirstlane(p0.y);
                aE += ea[(size_t)e0 * 32 + l32];
            }
        }
    }
    a0 += __shfl_xor(a0, 32, 64);
    a1 += __shfl_xor(a1, 32, 64);
    a2 += __shfl_xor(a2, 32, 64);
    a3 += __shfl_xor(a3, 32, 64);
    if (DO_EA) aE += __shfl_xor(aE, 32, 64);

    float inv = (end > beg) ? 1.0f / (float)(end - beg) : 0.0f;
    if (half == 0) {
        uint lo = (uint)f2b(a0 * inv) | ((uint)f2b(a1 * inv) << 16);
        uint hi = (uint)f2b(a2 * inv) | ((uint)f2b(a3 * inv) << 16);
        *reinterpret_cast<uint2*>(meanb + (size_t)v * 128 + l32 * 4) =
            make_uint2(lo, hi);
        if (DO_EA) aggEb[(size_t)v * 32 + l32] = f2b(aE * inv);
    }
    if (DO_EA && lane == 0) invc[v] = inv;
}

// ---------------------------------------------------------------------------
// fused MFMA GEMM, 64-row tile; double-buffered gload16 + counted vmcnt.
// OUT_BF16: write h1 bf16 + int8/scale shadow (for layer-2 gather).
template<bool OUT_BF16>
__global__ __launch_bounds__(256)
void gemmF_kernel(const ushort* __restrict__ Xb, const ushort* __restrict__ meanb,
                  const ushort* __restrict__ aggEb, const float* __restrict__ invc,
                  const ushort* __restrict__ Btp, const float* __restrict__ r,
                  const float* __restrict__ bu, const float* __restrict__ g,
                  const float* __restrict__ beta,
                  float* __restrict__ Cf, ushort* __restrict__ Cb,
                  unsigned char* __restrict__ Cq, float* __restrict__ Csc, int M) {
    __shared__ __align__(16) ushort Als[2][4][64][8];
    __shared__ __align__(16) ushort Bls[2][4][128][8];
    __shared__ float ps[2][64], ps2[2][64], psM[2][64];

    const int tid = threadIdx.x;
    const int wid = tid >> 6, lane = tid & 63;
    const int wr = wid >> 1, wc = wid & 1;
    const int lo4 = lane >> 4, li = lane & 15;
    const int brow = blockIdx.x * 64;

    f32x4 acc[2][4];
#pragma unroll
    for (int fr = 0; fr < 2; fr++)
#pragma unroll
        for (int fc = 0; fc < 4; fc++) acc[fr][fc] = (f32x4)0.f;

    const int akc  = wid;
    const int grow = brow + lane;

    auto stage = [&](int bf, int st) {
        int kg = st * 4 + akc;
        const ushort* gA;
        if (kg < 16)      gA = Xb    + (size_t)grow * 128 + kg * 8;
        else if (kg < 32) gA = meanb + (size_t)grow * 128 + (kg - 16) * 8;
        else              gA = aggEb + (size_t)grow * 32  + (kg - 32) * 8;
        gload16(gA, &Als[bf][akc][0][0]);
#pragma unroll
        for (int h = 0; h < 2; h++) {
            int ub = h * 256 + akc * 64;
            gload16(Btp + ((size_t)st * 512 + ub + lane) * 8,
                    &Bls[bf][0][0][0] + (size_t)ub * 8);
        }
    };

    stage(0, 0);
    int cur = 0;
    for (int step = 0; step < 9; step++) {
        if (step < 8) {
            stage(cur ^ 1, step + 1);
            asm volatile("s_waitcnt vmcnt(3)" ::: "memory");
        } else {
            asm volatile("s_waitcnt vmcnt(0)" ::: "memory");
        }
        __builtin_amdgcn_sched_barrier(0);
        __builtin_amdgcn_s_barrier();

        bf16x8 a0 = *reinterpret_cast<const bf16x8*>(&Als[cur][lo4][wr * 32 + li][0]);
        bf16x8 a1 = *reinterpret_cast<const bf16x8*>(&Als[cur][lo4][wr * 32 + 16 + li][0]);
#pragma unroll
        for (int fc = 0; fc < 4; fc++) {
            bf16x8 b = *reinterpret_cast<const bf16x8*>(&Bls[cur][lo4][wc * 64 + fc * 16 + li][0]);
            acc[0][fc] = __builtin_amdgcn_mfma_f32_16x16x32_bf16(a0, b, acc[0][fc], 0, 0, 0);
            acc[1][fc] = __builtin_amdgcn_mfma_f32_16x16x32_bf16(a1, b, acc[1][fc], 0, 0, 0);
        }
        __builtin_amdgcn_s_barrier();
        cur ^= 1;
    }

    float bu8[4], r8[4], g8[4], be8[4];
#pragma unroll
    for (int fc = 0; fc < 4; fc++) {
        int col = wc * 64 + fc * 16 + li;
        bu8[fc] = bu[col]; r8[fc] = r[col]; g8[fc] = g[col]; be8[fc] = beta[col];
    }

    float sv[2][4], s2v[2][4];
#pragma unroll
    for (int fr = 0; fr < 2; fr++)
#pragma unroll
        for (int j = 0; j < 4; j++) {
            int gr = brow + wr * 32 + fr * 16 + lo4 * 4 + j;
            float hv = 0.f;
            if (gr < M) hv = (invc[gr] > 0.f) ? 1.f : 0.f;
            float s = 0.f, s2 = 0.f;
#pragma unroll
            for (int fc = 0; fc < 4; fc++) {
                float val = acc[fr][fc][j] + bu8[fc] + hv * r8[fc];
                val = fmaxf(val, 0.f);
                acc[fr][fc][j] = val;
                s += val; s2 += val * val;
            }
#pragma unroll
            for (int m = 1; m < 16; m <<= 1) {
                s  += __shfl_xor(s, m, 64);
                s2 += __shfl_xor(s2, m, 64);
            }
            sv[fr][j] = s; s2v[fr][j] = s2;
        }

    if (li == 0) {
#pragma unroll
        for (int fr = 0; fr < 2; fr++)
#pragma unroll
            for (int j = 0; j < 4; j++) {
                int row64 = wr * 32 + fr * 16 + lo4 * 4 + j;
                ps[wc][row64]  = sv[fr][j];
                ps2[wc][row64] = s2v[fr][j];
            }
    }
    __syncthreads();

    float mean_[2][4], rstd_[2][4], lmax[2][4];
#pragma unroll
    for (int fr = 0; fr < 2; fr++)
#pragma unroll
        for (int j = 0; j < 4; j++) {
            int row64 = wr * 32 + fr * 16 + lo4 * 4 + j;
            int gr = brow + row64;
            float s  = sv[fr][j]  + ps[1 - wc][row64];
            float s2 = s2v[fr][j] + ps2[1 - wc][row64];
            float mean = s * (1.0f / 128.0f);
            float var  = s2 * (1.0f / 128.0f) - mean * mean;
            float rstd = rsqrtf(var + 1e-5f);
            mean_[fr][j] = mean; rstd_[fr][j] = rstd;
            float lm = 0.f;
            if (gr < M) {
#pragma unroll
                for (int fc = 0; fc < 4; fc++) {
                    int col = wc * 64 + fc * 16 + li;
                    float o = (acc[fr][fc][j] - mean) * rstd * g8[fc] + be8[fc];
                    if (OUT_BF16) Cb[(size_t)gr * 128 + col] = f2b(o);
                    else          Cf[(size_t)gr * 128 + col] = o;
                    lm = fmaxf(lm, fabsf(o));
                }
            }
            lmax[fr][j] = lm;
        }

    if (OUT_BF16) {
        // row absmax: reduce over li, then cross-wave via LDS
#pragma unroll
        for (int fr = 0; fr < 2; fr++)
#pragma unroll
            for (int j = 0; j < 4; j++) {
#pragma unroll
                for (int m = 1; m < 16; m <<= 1)
                    lmax[fr][j] = fmaxf(lmax[fr][j], __shfl_xor(lmax[fr][j], m, 64));
            }
        if (li == 0) {
#pragma unroll
            for (int fr = 0; fr < 2; fr++)
#pragma unroll
                for (int j = 0; j < 4; j++) {
                    int row64 = wr * 32 + fr * 16 + lo4 * 4 + j;
                    psM[wc][row64] = lmax[fr][j];
                }
        }
        __syncthreads();
#pragma unroll
        for (int fr = 0; fr < 2; fr++)
#pragma unroll
            for (int j = 0; j < 4; j++) {
                int row64 = wr * 32 + fr * 16 + lo4 * 4 + j;
                int gr = brow + row64;
                float rmax = fmaxf(psM[0][row64], psM[1][row64]);
                float senc = (rmax > 0.f) ? 127.0f / rmax : 0.f;
                if (gr < M) {
#pragma unroll
                    for (int fc = 0; fc < 4; fc++) {
                        int col = wc * 64 + fc * 16 + li;
                        float o = (acc[fr][fc][j] - mean_[fr][j]) * rstd_[fr][j] * g8[fc] + be8[fc];
                        int q = (int)rintf(o * senc);
                        Cq[(size_t)gr * 128 + col] = (unsigned char)(char)q;
                    }
                    if (li == 0 && wc == 0)
                        Csc[gr] = rmax * (1.0f / 127.0f);
                }
            }
    }
}

// ---------------------------------------------------------------------------
extern "C" void kernel_launch(void* const* d_in, const int* in_sizes, int n_in,
                              void* d_out, int out_size, void* d_ws, size_t ws_size,
                              hipStream_t stream)
{
    const float* x    = (const float*)d_in[0];
    const int*   ei   = (const int*)d_in[1];
    const float* ea   = (const float*)d_in[2];
    const float* Wn1  = (const float*)d_in[3];
    const float* bn1  = (const float*)d_in[4];
    const float* We1  = (const float*)d_in[5];
    const float* be1  = (const float*)d_in[6];
    const float* Wu1  = (const float*)d_in[7];
    const float* bu1  = (const float*)d_in[8];
    const float* g1   = (const float*)d_in[9];
    const float* beta1= (const float*)d_in[10];
    const float* Wn2  = (const float*)d_in[11];
    const float* bn2  = (const float*)d_in[12];
    const float* We2  = (const float*)d_in[13];
    const float* be2  = (const float*)d_in[14];
    const float* Wu2  = (const float*)d_in[15];
    const float* bu2  = (const float*)d_in[16];
    const float* g2   = (const float*)d_in[17];
    const float* beta2= (const float*)d_in[18];

    const int* srcI = ei;
    const int* dstI = ei + NE;
    float* out = (float*)d_out;

    // ---- workspace layout
    float* invc = (float*)d_ws;                        // N
    int*   rp   = (int*)(invc + NN);                   // N+1
    int*   hist = rp + NN + 1;                         // N
    int*   psum = hist + NN;                           // 256
    uintptr_t pbase = ((uintptr_t)(psum + 256) + 7) & ~(uintptr_t)7;
    int2*  pairs = (int2*)pbase;                       // E (8B each)
    uintptr_t base = ((uintptr_t)(pairs + NE) + 15) & ~(uintptr_t)15;
    ushort* Xb    = (ushort*)base;                     // N*128 bf16 (also h1)
    ushort* meanb = Xb + (size_t)NN * 128;             // N*128
    ushort* aggEb = meanb + (size_t)NN * 128;          // N*32
    ushort* Btp1  = aggEb + (size_t)NN * 32;           // 36*128*8
    ushort* Btp2  = Btp1 + NOCT * 1024;
    float*  r1    = (float*)(Btp2 + NOCT * 1024);      // 128
    float*  r2    = r1 + 128;
    float*  sc    = r2 + 128;                          // N (gather scales)
    uintptr_t qbase = ((uintptr_t)(sc + NN) + 15) & ~(uintptr_t)15;
    uint*   Xq32  = (uint*)qbase;                      // N*32 uints (int8 rows)

    const int gemm_grid = (NN + 63) / 64;

    // ---- setup: zero hist, then merged prep1|prep2|castq|hist
    hipMemsetAsync(hist, 0, NN * sizeof(int), stream);
    init_kernel<<<CASTQ_BLOCKS + HIST_BLOCKS + 2 * PREP_BLOCKS, 256, 0, stream>>>(
        x, Xb, Xq32, sc, dstI, hist,
        Wn1, bn1, We1, be1, Wu1, Btp1, r1,
        Wn2, bn2, We2, be2, Wu2, Btp2, r2);

    // ---- CSR build
    scan1_kernel<<<NBLK, 256, 0, stream>>>(hist, rp, psum);
    scan23_kernel<<<NBLK, 256, 0, stream>>>(rp, psum);
    place_kernel<<<2048, 256, 0, stream>>>(srcI, dstI, rp, hist, pairs, NE);

    // ---- layer 1
    agg_kernel<true><<<(NN + 3) / 4, 256, 0, stream>>>(Xq32, sc, ea, pairs, rp,
                                                       meanb, aggEb, invc);
    gemmF_kernel<true><<<gemm_grid, 256, 0, stream>>>(
        Xb, meanb, aggEb, invc, Btp1, r1, bu1, g1, beta1,
        nullptr, Xb, (unsigned char*)Xq32, sc, NN);

    // ---- layer 2 (Xb/Xq32/sc now hold h1)
    agg_kernel<false><<<(NN + 3) / 4, 256, 0, stream>>>(Xq32, sc, ea, pairs, rp,
                                                        meanb, aggEb, invc);
    gemmF_kernel<false><<<gemm_grid, 256, 0, stream>>>(
        Xb, meanb, aggEb, invc, Btp2, r2, bu2, g2, beta2,
        out, nullptr, nullptr, nullptr, NN);
}